// Round 6
// baseline (2927.266 us; speedup 1.0000x reference)
//
#include <hip/hip_runtime.h>
#include <math.h>

#define N_NODES 100000
#define NE 1000000
#define D_NODE 64
#define D_EDGE 32
#define HID 64
#define H2C 32
#define D_IN 160
#define EPS_LOGIT 0.012f
#define EPS_F32 1e-3f

typedef __attribute__((ext_vector_type(8))) short short8;   // 8 bf16
typedef __attribute__((ext_vector_type(4))) float f32x4;
typedef __attribute__((ext_vector_type(4))) unsigned short ushort4v;

// ws byte layout (v6 path):
//  [0,16)                 flag counter
//  [16, +8192)            a1 frags (W1e, bf16 hi|lo): [4 mm][64 lane][16]
//  [8208, +8192)          a2 frags (W2, bf16 hi|lo):  [2 mm2 x 2 kk][64 lane][16]
//  [16448, +12.8MB)       U bf16 [100000][64]  (= nf@W1s^T + b1)
//  [12816448, +12.8MB)    V bf16 [100000][64]  (= nf@W1t^T)
//  [25616448, +1MB)       flag list (262144 entries)
#define WS_A1_OFF 16
#define WS_A2_OFF (WS_A1_OFF + 8192)
#define WS_U_OFF  16448
#define WS_V_OFF  (WS_U_OFF + N_NODES*HID*2)
#define WS_LIST_OFF (WS_V_OFF + N_NODES*HID*2)
#define WS_LIST_CAP 262144
#define WS_V6_MIN (WS_LIST_OFF + WS_LIST_CAP*4)

__device__ __forceinline__ unsigned short bf16_rne(float x) {
    unsigned int u = __float_as_uint(x);
    u += 0x7fffu + ((u >> 16) & 1u);
    return (unsigned short)(u >> 16);
}
__device__ __forceinline__ float bf16_tof(unsigned short h) {
    return __uint_as_float(((unsigned int)h) << 16);
}
__device__ __forceinline__ void split8(const float* xs, short8& hi, short8& lo) {
    #pragma unroll
    for (int i = 0; i < 8; ++i) {
        unsigned short h = bf16_rne(xs[i]);
        float fh = bf16_tof(h);
        unsigned short l = bf16_rne(xs[i] - fh);
        hi[i] = (short)h;
        lo[i] = (short)l;
    }
}

// ---- Prep 1: per-node U = nf@W1s^T + b1, V = nf@W1t^T (f32-exact, bf16 out) ----
__global__ __launch_bounds__(256, 2) void prep_uv_kernel(
    const float* __restrict__ nf, const float* __restrict__ W1,
    const float* __restrict__ b1,
    unsigned short* __restrict__ U, unsigned short* __restrict__ V)
{
    const int wave = threadIdx.x >> 6, lane = threadIdx.x & 63;  // lane = hidden j
    float w[128];
    #pragma unroll
    for (int q = 0; q < 32; ++q) {
        const float4 t = *(const float4*)(W1 + lane * D_IN + q * 4);
        w[q*4+0]=t.x; w[q*4+1]=t.y; w[q*4+2]=t.z; w[q*4+3]=t.w;
    }
    const float bj = b1[lane];
    const int node0 = (blockIdx.x * 4 + wave) * 32;
    #pragma unroll 1
    for (int ni = 0; ni < 32; ++ni) {
        const int node = node0 + ni;
        if (node >= N_NODES) return;
        const float xj = nf[(size_t)node * 64 + lane];
        float u = bj, v = 0.f;
        #pragma unroll
        for (int k = 0; k < 64; ++k) {
            const float xk = __shfl(xj, k, 64);
            u = fmaf(xk, w[k], u);
            v = fmaf(xk, w[64 + k], v);
        }
        U[(size_t)node*64 + lane] = bf16_rne(u);
        V[(size_t)node*64 + lane] = bf16_rne(v);
    }
}

// ---- Prep 2: pack W1e / W2 A-side MFMA fragments (bf16 hi|lo), zero counter ----
__global__ void prep_pack_v6(const float* __restrict__ W1, const float* __restrict__ W2,
                             unsigned char* __restrict__ ws)
{
    const int t = blockIdx.x * blockDim.x + threadIdx.x;
    if (t == 0) *(int*)ws = 0;
    unsigned short* a1 = (unsigned short*)(ws + WS_A1_OFF);
    unsigned short* a2 = (unsigned short*)(ws + WS_A2_OFF);
    for (int task = t; task < 512; task += gridDim.x * blockDim.x) {
        const int isA2 = task >= 256;
        const int tt = task & 255;
        const int f = tt >> 6, l = tt & 63;
        const int l15 = l & 15, kg = l >> 4;
        const float* src;
        unsigned short* dst;
        if (!isA2) {  // a1[mm]: A row m = hidden (mm*16+l15), k = ef dim (kg*8+i)
            src = W1 + (size_t)(f*16 + l15)*D_IN + 128 + kg*8;
            dst = a1 + ((size_t)f*64 + l)*16;
        } else {      // a2[mm2*2+kk]: A row m = h2 unit, k = hid (kk*32+kg*8+i)
            const int mm2 = f >> 1, kk = f & 1;
            src = W2 + (size_t)(mm2*16 + l15)*HID + kk*32 + kg*8;
            dst = a2 + ((size_t)f*64 + l)*16;
        }
        #pragma unroll
        for (int i = 0; i < 8; ++i) {
            const float wv = src[i];
            const unsigned short h = bf16_rne(wv);
            dst[i] = h;
            dst[8+i] = bf16_rne(wv - bf16_tof(h));
        }
    }
}

// ---- Main v6: 16 edges per wave; C col = edge, row = hidden ----
__global__ __launch_bounds__(256, 4) void edge_mlp_v6_kernel(
    const int* __restrict__ ei, const float* __restrict__ ef,
    const float* __restrict__ b2, const float* __restrict__ W3, const float* __restrict__ b3,
    const unsigned short* __restrict__ a1p, const unsigned short* __restrict__ a2p,
    const unsigned short* __restrict__ U, const unsigned short* __restrict__ V,
    int* __restrict__ counter, int* __restrict__ list, int cap,
    float* __restrict__ out)
{
    // padded to 88: 176B row stride = 16B-aligned, <=2-way LDS banks
    __shared__ __attribute__((aligned(16))) unsigned short h1hi[4][16][88];
    __shared__ __attribute__((aligned(16))) unsigned short h1lo[4][16][88];
    const int wave = threadIdx.x >> 6, lane = threadIdx.x & 63;
    const int l15 = lane & 15, kg = lane >> 4;
    const long long e = (long long)blockIdx.x * 64 + wave * 16 + l15;

    const int is64 = (ei[1]==0)&(ei[3]==0)&(ei[5]==0)&(ei[7]==0);
    int si, ti;
    if (is64) { si = ei[(size_t)(2*e)]; ti = ei[(size_t)(2*(NE+e))]; }
    else      { si = ei[(size_t)e];     ti = ei[(size_t)(NE+e)]; }

    // node-table gathers, directly in C-fragment layout (1 line per row)
    ushort4v uf[4], vf[4];
    #pragma unroll
    for (int mm = 0; mm < 4; ++mm) {
        uf[mm] = *(const ushort4v*)(U + (size_t)si*64 + mm*16 + kg*4);
        vf[mm] = *(const ushort4v*)(V + (size_t)ti*64 + mm*16 + kg*4);
    }
    // ef B-fragment (streaming): lane reads ef[e][kg*8 .. +8], full bf16x2
    const float* efp = ef + (size_t)e * D_EDGE + kg*8;
    const float4 fe0 = *(const float4*)efp;
    const float4 fe1 = *(const float4*)(efp+4);
    float exs[8] = {fe0.x,fe0.y,fe0.z,fe0.w,fe1.x,fe1.y,fe1.z,fe1.w};
    short8 bhi, blo;
    split8(exs, bhi, blo);

    // Layer 1 ef-part: 4 M-tiles of hidden, K=32
    const f32x4 z4 = {0.f,0.f,0.f,0.f};
    f32x4 acc1[4];
    #pragma unroll
    for (int mm = 0; mm < 4; ++mm) {
        const unsigned short* fp = a1p + ((size_t)mm*64 + lane)*16;
        const short8 ahi = *(const short8*)fp;
        const short8 alo = *(const short8*)(fp + 8);
        f32x4 a = z4;
        a = __builtin_amdgcn_mfma_f32_16x16x32_bf16(ahi, bhi, a, 0,0,0);
        a = __builtin_amdgcn_mfma_f32_16x16x32_bf16(ahi, blo, a, 0,0,0);
        a = __builtin_amdgcn_mfma_f32_16x16x32_bf16(alo, bhi, a, 0,0,0);
        acc1[mm] = a;
    }

    // p = ef-part + u + v (b1 folded into U); ReLU; split; to LDS [edge][hid]
    #pragma unroll
    for (int mm = 0; mm < 4; ++mm) {
        unsigned int hp[2], lp[2];
        #pragma unroll
        for (int r2 = 0; r2 < 2; ++r2) {
            unsigned short hh[2], ll[2];
            #pragma unroll
            for (int q = 0; q < 2; ++q) {
                const int r = r2*2+q;
                float p = acc1[mm][r] + bf16_tof((unsigned short)uf[mm][r])
                                      + bf16_tof((unsigned short)vf[mm][r]);
                p = fmaxf(p, 0.f);
                const unsigned short h = bf16_rne(p);
                hh[q] = h; ll[q] = bf16_rne(p - bf16_tof(h));
            }
            hp[r2] = (unsigned int)hh[0] | ((unsigned int)hh[1] << 16);
            lp[r2] = (unsigned int)ll[0] | ((unsigned int)ll[1] << 16);
        }
        *(uint2*)&h1hi[wave][l15][mm*16 + kg*4] = make_uint2(hp[0], hp[1]);
        *(uint2*)&h1lo[wave][l15][mm*16 + kg*4] = make_uint2(lp[0], lp[1]);
    }
    asm volatile("s_waitcnt lgkmcnt(0)" ::: "memory");  // wave-private slice; no barrier needed

    // Layer 2: A = W2 (2 M-tiles), B = h1 (K=64 over 2 kk)
    f32x4 acc2[2] = {z4, z4};
    #pragma unroll
    for (int kk = 0; kk < 2; ++kk) {
        const short8 bh = *(const short8*)&h1hi[wave][l15][kk*32 + kg*8];
        const short8 bl = *(const short8*)&h1lo[wave][l15][kk*32 + kg*8];
        #pragma unroll
        for (int mm2 = 0; mm2 < 2; ++mm2) {
            const unsigned short* fp = a2p + ((size_t)(mm2*2+kk)*64 + lane)*16;
            const short8 ah = *(const short8*)fp;
            const short8 al = *(const short8*)(fp + 8);
            acc2[mm2] = __builtin_amdgcn_mfma_f32_16x16x32_bf16(ah, bh, acc2[mm2],0,0,0);
            acc2[mm2] = __builtin_amdgcn_mfma_f32_16x16x32_bf16(ah, bl, acc2[mm2],0,0,0);
            acc2[mm2] = __builtin_amdgcn_mfma_f32_16x16x32_bf16(al, bh, acc2[mm2],0,0,0);
        }
    }
    asm volatile("s_waitcnt lgkmcnt(0)" ::: "memory");

    // Layer 3 + cross-kg reduce (lanes l15, l15+16, +32, +48 hold same edge)
    float part = 0.f;
    #pragma unroll
    for (int mm2 = 0; mm2 < 2; ++mm2)
        #pragma unroll
        for (int r = 0; r < 4; ++r) {
            const int h2 = mm2*16 + kg*4 + r;
            part += fmaxf(acc2[mm2][r] + b2[h2], 0.f) * W3[h2];
        }
    part += __shfl_xor(part, 16, 64);
    part += __shfl_xor(part, 32, 64);
    if (kg == 0) {
        const float logit = part + b3[0];
        const float sc = 1.f/(1.f + expf(-logit));
        out[e] = sc;
        out[NE + e] = (sc >= 0.5f) ? 1.f : 0.f;
        if (fabsf(logit) < EPS_LOGIT) {
            const int idx = atomicAdd(counter, 1);
            if (idx < cap) list[idx] = (int)e;
        }
    }
}

// ---- f64 wave-per-edge fixup (4-way ILP chains) ----
__global__ __launch_bounds__(256) void fixup_wave_f64_kernel(
    const float* __restrict__ nf, const int* __restrict__ ei,
    const float* __restrict__ ef,
    const float* __restrict__ W1, const float* __restrict__ b1,
    const float* __restrict__ W2, const float* __restrict__ b2,
    const float* __restrict__ W3, const float* __restrict__ b3,
    const int* __restrict__ counter, const int* __restrict__ list, int cap,
    float* __restrict__ out)
{
    __shared__ double fh[4][HID];
    const int wave = threadIdx.x >> 6, lane = threadIdx.x & 63;
    const int nwaves = (gridDim.x * blockDim.x) >> 6;
    const int wid = (blockIdx.x * blockDim.x + threadIdx.x) >> 6;
    int n = counter[0]; if (n > cap) n = cap;
    const int is64 = (ei[1]==0)&(ei[3]==0)&(ei[5]==0)&(ei[7]==0);

    for (int i = wid; i < n; i += nwaves) {
        const int e = list[i];
        int si, ti;
        if (is64) { si = ei[(size_t)2*e]; ti = ei[(size_t)2*(NE + (long long)e)]; }
        else      { si = ei[e];           ti = ei[NE + (size_t)e]; }
        const float* sp = nf + (size_t)si * D_NODE;
        const float* tp = nf + (size_t)ti * D_NODE;
        const float* ep = ef + (size_t)e * D_EDGE;

        const double* wr = (const double*)0;  // silence unused warnings pattern
        (void)wr;
        double a0 = (double)b1[lane], a1 = 0.0, a2 = 0.0, a3 = 0.0;
        const float* w1r = W1 + (size_t)lane * D_IN;
        #pragma unroll 4
        for (int k = 0; k < 64; k += 4) {
            a0 = fma((double)sp[k+0], (double)w1r[k+0], a0);
            a1 = fma((double)sp[k+1], (double)w1r[k+1], a1);
            a2 = fma((double)sp[k+2], (double)w1r[k+2], a2);
            a3 = fma((double)sp[k+3], (double)w1r[k+3], a3);
        }
        #pragma unroll 4
        for (int k = 0; k < 64; k += 4) {
            a0 = fma((double)tp[k+0], (double)w1r[64+k+0], a0);
            a1 = fma((double)tp[k+1], (double)w1r[64+k+1], a1);
            a2 = fma((double)tp[k+2], (double)w1r[64+k+2], a2);
            a3 = fma((double)tp[k+3], (double)w1r[64+k+3], a3);
        }
        #pragma unroll 4
        for (int k = 0; k < 32; k += 4) {
            a0 = fma((double)ep[k+0], (double)w1r[128+k+0], a0);
            a1 = fma((double)ep[k+1], (double)w1r[128+k+1], a1);
            a2 = fma((double)ep[k+2], (double)w1r[128+k+2], a2);
            a3 = fma((double)ep[k+3], (double)w1r[128+k+3], a3);
        }
        fh[wave][lane] = fmax((a0 + a1) + (a2 + a3), 0.0);
        asm volatile("s_waitcnt lgkmcnt(0)" ::: "memory");

        double tsum = 0.0;
        if (lane < H2C) {
            double h0 = (double)b2[lane], h1 = 0.0, h2 = 0.0, h3 = 0.0;
            const float* w2r = W2 + (size_t)lane * HID;
            #pragma unroll 4
            for (int j = 0; j < 64; j += 4) {
                h0 = fma(fh[wave][j+0], (double)w2r[j+0], h0);
                h1 = fma(fh[wave][j+1], (double)w2r[j+1], h1);
                h2 = fma(fh[wave][j+2], (double)w2r[j+2], h2);
                h3 = fma(fh[wave][j+3], (double)w2r[j+3], h3);
            }
            tsum = fmax((h0 + h1) + (h2 + h3), 0.0) * (double)W3[lane];
        }
        #pragma unroll
        for (int off = 1; off < 32; off <<= 1) tsum += __shfl_xor(tsum, off, 32);
        if (lane == 0) {
            const double logit = tsum + (double)b3[0];
            const float sc = (float)(1.0 / (1.0 + exp(-logit)));
            out[e] = sc;
            out[NE + (size_t)e] = (sc >= 0.5f) ? 1.0f : 0.0f;
        }
        asm volatile("s_waitcnt lgkmcnt(0)" ::: "memory");
    }
}

// ---------- Fallback (tiny ws): proven f32 VALU path ----------
__global__ void zero_counter_kernel(int* __restrict__ c) {
    if (blockIdx.x == 0 && threadIdx.x == 0) c[0] = 0;
}

__global__ __launch_bounds__(256, 4) void edge_mlp_f32_kernel(
    const float* __restrict__ nf, const int* __restrict__ ei,
    const float* __restrict__ ef,
    const float* __restrict__ W1, const float* __restrict__ b1,
    const float* __restrict__ W2, const float* __restrict__ b2,
    const float* __restrict__ W3, const float* __restrict__ b3,
    int* __restrict__ counter, int* __restrict__ list, int cap,
    float* __restrict__ out)
{
    const int e = blockIdx.x * blockDim.x + threadIdx.x;
    if (e >= NE) return;
    const int is64 = (ei[1]==0)&(ei[3]==0)&(ei[5]==0)&(ei[7]==0);
    int si, ti;
    if (is64) { si = ei[2*(size_t)e]; ti = ei[2*((size_t)NE + e)]; }
    else      { si = ei[e];           ti = ei[NE + e]; }
    const float* srcp = nf + (size_t)si * D_NODE;
    const float* tgtp = nf + (size_t)ti * D_NODE;
    const float* efp  = ef + (size_t)e  * D_EDGE;

    float acc[HID];
    #pragma unroll
    for (int j = 0; j < HID; ++j) acc[j] = b1[j];
    #pragma unroll 1
    for (int kc = 0; kc < D_IN / 16; ++kc) {
        const float* base = (kc < 4) ? (srcp + kc * 16)
                          : (kc < 8) ? (tgtp + (kc - 4) * 16)
                                     : (efp  + (kc - 8) * 16);
        float c[16];
        #pragma unroll
        for (int q = 0; q < 4; ++q) {
            const float4 v = *reinterpret_cast<const float4*>(base + q * 4);
            c[q*4+0]=v.x; c[q*4+1]=v.y; c[q*4+2]=v.z; c[q*4+3]=v.w;
        }
        #pragma unroll
        for (int j = 0; j < HID; ++j)
            #pragma unroll
            for (int q = 0; q < 16; ++q)
                acc[j] = fmaf(c[q], W1[j*D_IN + kc*16 + q], acc[j]);
    }
    #pragma unroll
    for (int j = 0; j < HID; ++j) acc[j] = fmaxf(acc[j], 0.0f);

    float logit = b3[0];
    #pragma unroll 1
    for (int jj = 0; jj < H2C; ++jj) {
        float h = b2[jj];
        #pragma unroll
        for (int j = 0; j < HID; ++j) h = fmaf(acc[j], W2[jj*HID + j], h);
        logit = fmaf(fmaxf(h, 0.0f), W3[jj], logit);
    }
    const float score = 1.0f / (1.0f + expf(-logit));
    out[e] = score;
    out[(size_t)NE + e] = (score >= 0.5f) ? 1.0f : 0.0f;
    if (fabsf(logit) < EPS_F32) {
        const int idx = atomicAdd(counter, 1);
        if (idx < cap) list[idx] = e;
    }
}

extern "C" void kernel_launch(void* const* d_in, const int* in_sizes, int n_in,
                              void* d_out, int out_size, void* d_ws, size_t ws_size,
                              hipStream_t stream) {
    const float* nf = (const float*)d_in[0];
    const int*   ei = (const int*)  d_in[1];
    const float* ef = (const float*)d_in[2];
    const float* W1 = (const float*)d_in[3];
    const float* b1 = (const float*)d_in[4];
    const float* W2 = (const float*)d_in[5];
    const float* b2 = (const float*)d_in[6];
    const float* W3 = (const float*)d_in[7];
    const float* b3 = (const float*)d_in[8];
    float* out = (float*)d_out;
    unsigned char* ws = (unsigned char*)d_ws;
    int* counter = (int*)ws;

    if (ws_size >= (size_t)WS_V6_MIN) {
        unsigned short* U = (unsigned short*)(ws + WS_U_OFF);
        unsigned short* V = (unsigned short*)(ws + WS_V_OFF);
        int* list = (int*)(ws + WS_LIST_OFF);
        hipLaunchKernelGGL(prep_uv_kernel, dim3(782), dim3(256), 0, stream,
                           nf, W1, b1, U, V);
        hipLaunchKernelGGL(prep_pack_v6, dim3(2), dim3(256), 0, stream, W1, W2, ws);
        hipLaunchKernelGGL(edge_mlp_v6_kernel, dim3(NE/64), dim3(256), 0, stream,
                           ei, ef, b2, W3, b3,
                           (const unsigned short*)(ws + WS_A1_OFF),
                           (const unsigned short*)(ws + WS_A2_OFF),
                           U, V, counter, list, WS_LIST_CAP, out);
        hipLaunchKernelGGL(fixup_wave_f64_kernel, dim3(512), dim3(256), 0, stream,
                           nf, ei, ef, W1, b1, W2, b2, W3, b3,
                           counter, list, WS_LIST_CAP, out);
    } else {
        long long cap_ll = ((long long)ws_size - 16) / 4;
        const int cap = (int)(cap_ll < 0 ? 0 : (cap_ll > NE ? NE : cap_ll));
        int* slist = (int*)(ws + 16);
        hipLaunchKernelGGL(zero_counter_kernel, dim3(1), dim3(64), 0, stream, counter);
        hipLaunchKernelGGL(edge_mlp_f32_kernel, dim3((NE + 255)/256), dim3(256), 0, stream,
                           nf, ei, ef, W1, b1, W2, b2, W3, b3, counter, slist, cap, out);
        hipLaunchKernelGGL(fixup_wave_f64_kernel, dim3(512), dim3(256), 0, stream,
                           nf, ei, ef, W1, b1, W2, b2, W3, b3, counter, slist, cap, out);
    }
}

// Round 7
// 1626.630 us; speedup vs baseline: 1.7996x; 1.7996x over previous
//
#include <hip/hip_runtime.h>
#include <math.h>

#define N_NODES 100000
#define NE 1000000
#define D_NODE 64
#define D_EDGE 32
#define HID 64
#define H2C 32
#define D_IN 160
#define EPS1 0.012f   // bf16-UV error bound (validated: round 6 passed with it)
#define EPS2 1e-3f    // f32-path error bound (validated: rounds 3-5)

typedef __attribute__((ext_vector_type(8))) short short8;   // 8 bf16
typedef __attribute__((ext_vector_type(4))) float f32x4;

// ws byte layout (v7 path):
//  [0,4) counter1  [4,8) counter2  [8,16) pad
//  [16, +8192)          a1 frags (W1e bf16 hi|lo): [4 nn][64 lane][16]
//  [8208, +8192)        a2 frags (W2 bf16 hi|lo):  [4 f][64 lane][16]
//  [16640, +12.8MB)     Uhi bf16 [100K][64]   (= nf@W1s^T + b1)
//  [+12.8MB)            Ulo bf16 [100K][64]
//  [+12.8MB)            Vhi bf16 [100K][64]   (= nf@W1t^T)
//  [+12.8MB)            Vlo bf16 [100K][64]
//  [51216640, +1.6MB)   list1 (400000 ints)
//  [52816640, +256KB)   list2 (65536 ints)
#define WS_A1_OFF 16
#define WS_A2_OFF 8208
#define WS_UHI 16640
#define TBL_BYTES (N_NODES * HID * 2)          // 12,800,000
#define WS_ULO (WS_UHI + TBL_BYTES)
#define WS_VHI (WS_ULO + TBL_BYTES)
#define WS_VLO (WS_VHI + TBL_BYTES)
#define WS_L1_OFF (WS_VLO + TBL_BYTES)         // 51,216,640
#define L1_CAP 400000
#define WS_L2_OFF (WS_L1_OFF + L1_CAP * 4)     // 52,816,640
#define L2_CAP 65536
#define WS_V7_MIN (WS_L2_OFF + L2_CAP * 4)     // 53,078,784

__device__ __forceinline__ unsigned short bf16_rne(float x) {
    unsigned int u = __float_as_uint(x);
    u += 0x7fffu + ((u >> 16) & 1u);
    return (unsigned short)(u >> 16);
}
__device__ __forceinline__ float bf16_tof(unsigned short h) {
    return __uint_as_float(((unsigned int)h) << 16);
}
__device__ __forceinline__ void split8(const float* xs, short8& hi, short8& lo) {
    #pragma unroll
    for (int i = 0; i < 8; ++i) {
        unsigned short h = bf16_rne(xs[i]);
        float fh = bf16_tof(h);
        unsigned short l = bf16_rne(xs[i] - fh);
        hi[i] = (short)h;
        lo[i] = (short)l;
    }
}

// ---- Prep 1: per-node U = nf@W1s^T + b1, V = nf@W1t^T (f32), stored bf16 hi+lo ----
__global__ void prep_uv_kernel(const float* __restrict__ nf, const float* __restrict__ W1,
                               const float* __restrict__ b1,
                               unsigned short* __restrict__ Uhi, unsigned short* __restrict__ Ulo,
                               unsigned short* __restrict__ Vhi, unsigned short* __restrict__ Vlo)
{
    const int wave = threadIdx.x >> 6, lane = threadIdx.x & 63;  // lane = hidden j
    float w[128];
    #pragma unroll
    for (int q = 0; q < 32; ++q) {
        const float4 t = *(const float4*)(W1 + lane * D_IN + q * 4);
        w[q*4+0]=t.x; w[q*4+1]=t.y; w[q*4+2]=t.z; w[q*4+3]=t.w;
    }
    const float bj = b1[lane];
    const int node0 = (blockIdx.x * 4 + wave) * 8;   // 8 nodes per wave
    #pragma unroll 1
    for (int ni = 0; ni < 8; ++ni) {
        const int node = node0 + ni;
        if (node >= N_NODES) return;
        const float xj = nf[(size_t)node * 64 + lane];
        float u = bj, v = 0.f;
        #pragma unroll
        for (int k = 0; k < 64; ++k) {
            const float xk = __shfl(xj, k, 64);
            u = fmaf(xk, w[k], u);
            v = fmaf(xk, w[64 + k], v);
        }
        const unsigned short uh = bf16_rne(u), vh = bf16_rne(v);
        Uhi[(size_t)node*64 + lane] = uh;
        Ulo[(size_t)node*64 + lane] = bf16_rne(u - bf16_tof(uh));
        Vhi[(size_t)node*64 + lane] = vh;
        Vlo[(size_t)node*64 + lane] = bf16_rne(v - bf16_tof(vh));
    }
}

// ---- Prep 2: pack W1e / W2 B-side MFMA fragments (bf16 hi|lo), zero counters ----
__global__ void prep_pack_v7(const float* __restrict__ W1, const float* __restrict__ W2,
                             unsigned char* __restrict__ ws)
{
    const int t = blockIdx.x * blockDim.x + threadIdx.x;
    if (t == 0) { *(int*)ws = 0; *(int*)(ws + 4) = 0; }
    unsigned short* a1 = (unsigned short*)(ws + WS_A1_OFF);
    unsigned short* a2 = (unsigned short*)(ws + WS_A2_OFF);
    for (int task = t; task < 512; task += gridDim.x * blockDim.x) {
        const int isA2 = task >= 256;
        const int tt = task & 255;
        const int f = tt >> 6, l = tt & 63;
        const int l15 = l & 15, kg = l >> 4;
        const float* src;
        unsigned short* dst;
        if (!isA2) {  // a1[nn]: B n = hidden (f*16+l15), k = ef dim (kg*8+i)
            src = W1 + (size_t)(f*16 + l15)*D_IN + 128 + kg*8;
            dst = a1 + ((size_t)f*64 + l)*16;
        } else {      // a2[nn2*2+kk]: B n = h2 unit, k = hid (kk*32+kg*8+i)
            const int nn2 = f >> 1, kk = f & 1;
            src = W2 + (size_t)(nn2*16 + l15)*HID + kk*32 + kg*8;
            dst = a2 + ((size_t)f*64 + l)*16;
        }
        #pragma unroll
        for (int i = 0; i < 8; ++i) {
            const float wv = src[i];
            const unsigned short h = bf16_rne(wv);
            dst[i] = h;
            dst[8+i] = bf16_rne(wv - bf16_tof(h));
        }
    }
}

// ---- Main v7: round-4 wave shape (2 t-tiles x 16 edges) + bf16 U/V tables ----
__global__ __launch_bounds__(256) void edge_mlp_v7_kernel(
    const int* __restrict__ ei, const float* __restrict__ ef,
    const float* __restrict__ b2, const float* __restrict__ W3, const float* __restrict__ b3,
    const unsigned short* __restrict__ a1p, const unsigned short* __restrict__ a2p,
    const unsigned short* __restrict__ Uhi, const unsigned short* __restrict__ Vhi,
    int* __restrict__ counter, int* __restrict__ list, int cap,
    float* __restrict__ out)
{
    __shared__ __attribute__((aligned(16))) float Hs[4][16][68];
    const int wave = threadIdx.x >> 6, lane = threadIdx.x & 63;
    const int l15 = lane & 15, kg = lane >> 4;
    const long long e0 = (long long)blockIdx.x * 128 + wave * 32;

    const int is64 = (ei[1]==0)&(ei[3]==0)&(ei[5]==0)&(ei[7]==0);

    // ---- ei loads + ALL gathers + ef loads issued upfront (batched MLP) ----
    int si[2], ti[2];
    const float* efpp[2];
    #pragma unroll
    for (int t = 0; t < 2; ++t) {
        long long e = e0 + t * 16 + l15;
        if (e >= NE) e = NE - 1;  // tail clamp (writes masked later)
        if (is64) { si[t] = ei[(size_t)(2*e)]; ti[t] = ei[(size_t)(2*(NE+e))]; }
        else      { si[t] = ei[(size_t)e];     ti[t] = ei[(size_t)(NE+e)]; }
        efpp[t] = ef + (size_t)e * D_EDGE;
    }
    float4 efv[2][2];
    #pragma unroll
    for (int t = 0; t < 2; ++t) {
        efv[t][0] = *(const float4*)(efpp[t] + kg*8);
        efv[t][1] = *(const float4*)(efpp[t] + kg*8 + 4);
    }
    short8 uh[2][2], vh[2][2];   // [t][kk]: edge l15's u/v slice kk*32+kg*8..+8
    #pragma unroll
    for (int t = 0; t < 2; ++t)
        #pragma unroll
        for (int kk = 0; kk < 2; ++kk) {
            uh[t][kk] = *(const short8*)(Uhi + (size_t)si[t]*64 + kk*32 + kg*8);
            vh[t][kk] = *(const short8*)(Vhi + (size_t)ti[t]*64 + kk*32 + kg*8);
        }

    // ---- Layer 1 ef-part: A = edge ef rows, B = W1e frags (round-4 wiring) ----
    const f32x4 z4 = {0.f,0.f,0.f,0.f};
    f32x4 acc1[2][4];
    #pragma unroll
    for (int t = 0; t < 2; ++t) {
        float xs[8] = {efv[t][0].x,efv[t][0].y,efv[t][0].z,efv[t][0].w,
                       efv[t][1].x,efv[t][1].y,efv[t][1].z,efv[t][1].w};
        short8 ahi, alo;
        split8(xs, ahi, alo);
        #pragma unroll
        for (int nn = 0; nn < 4; ++nn) {
            const unsigned short* fp = a1p + ((size_t)nn*64 + lane)*16;
            const short8 bhi = *(const short8*)fp;
            const short8 blo = *(const short8*)(fp + 8);
            f32x4 a = z4;
            a = __builtin_amdgcn_mfma_f32_16x16x32_bf16(ahi, bhi, a, 0,0,0);
            a = __builtin_amdgcn_mfma_f32_16x16x32_bf16(ahi, blo, a, 0,0,0);
            a = __builtin_amdgcn_mfma_f32_16x16x32_bf16(alo, bhi, a, 0,0,0);
            acc1[t][nn] = a;
        }
    }

    const float b2a = b2[l15], b2b = b2[16 + l15];
    const float w3a = W3[l15], w3b = W3[16 + l15];
    const float b3s = b3[0];

    #pragma unroll
    for (int t = 0; t < 2; ++t) {
        // ef-part to LDS (C layout: row kg*4+r = edge, col nn*16+l15 = hidden)
        #pragma unroll
        for (int nn = 0; nn < 4; ++nn)
            #pragma unroll
            for (int r = 0; r < 4; ++r)
                Hs[wave][kg*4 + r][nn*16 + l15] = acc1[t][nn][r];
        asm volatile("s_waitcnt lgkmcnt(0)" ::: "memory");  // wave-private slice

        // Layer 2: A = h1 = relu(ef-part + u + v), B = W2 frags
        f32x4 acc2[2] = {z4, z4};
        #pragma unroll
        for (int kk = 0; kk < 2; ++kk) {
            const float* hp = &Hs[wave][l15][kk*32 + kg*8];
            float xs[8];
            #pragma unroll
            for (int i = 0; i < 8; ++i)
                xs[i] = fmaxf(hp[i] + bf16_tof((unsigned short)uh[t][kk][i])
                                    + bf16_tof((unsigned short)vh[t][kk][i]), 0.f);
            short8 a2hi, a2lo;
            split8(xs, a2hi, a2lo);
            #pragma unroll
            for (int nn = 0; nn < 2; ++nn) {
                const unsigned short* fp = a2p + ((size_t)(nn*2+kk)*64 + lane)*16;
                const short8 bhi = *(const short8*)fp;
                const short8 blo = *(const short8*)(fp + 8);
                acc2[nn] = __builtin_amdgcn_mfma_f32_16x16x32_bf16(a2hi, bhi, acc2[nn],0,0,0);
                acc2[nn] = __builtin_amdgcn_mfma_f32_16x16x32_bf16(a2hi, blo, acc2[nn],0,0,0);
                acc2[nn] = __builtin_amdgcn_mfma_f32_16x16x32_bf16(a2lo, bhi, acc2[nn],0,0,0);
            }
        }
        asm volatile("s_waitcnt lgkmcnt(0)" ::: "memory");

        // Layer 3 + reduce across l15 (= h2 units)
        float vv[4];
        #pragma unroll
        for (int r = 0; r < 4; ++r) {
            float x = fmaxf(acc2[0][r] + b2a, 0.f) * w3a + fmaxf(acc2[1][r] + b2b, 0.f) * w3b;
            #pragma unroll
            for (int off = 1; off < 16; off <<= 1) x += __shfl_xor(x, off, 16);
            vv[r] = x + b3s;
        }
        float lg = 0.f;
        bool valid = false;
        long long e = 0;
        if (l15 < 4) {
            lg = (l15 == 0) ? vv[0] : (l15 == 1) ? vv[1] : (l15 == 2) ? vv[2] : vv[3];
            e = e0 + t * 16 + kg * 4 + l15;
            valid = (e < NE);
            if (valid) {
                const float sc = 1.0f / (1.0f + expf(-lg));
                out[e] = sc;
                out[NE + e] = (sc >= 0.5f) ? 1.0f : 0.0f;
            }
        }
        // Wave-aggregated flag append (ONE atomic per wave, not per edge)
        const bool flag = valid && (fabsf(lg) < EPS1);
        const unsigned long long m = __ballot(flag);
        if (m) {
            const int leader = (int)(__ffsll((long long)m) - 1);
            int base = 0;
            if (lane == leader) base = atomicAdd(counter, (int)__popcll(m));
            base = __shfl(base, leader, 64);
            if (flag) {
                const int pos = base + (int)__popcll(m & ((1ull << lane) - 1ull));
                if (pos < cap) list[pos] = (int)e;
            }
        }
    }
}

// ---- Fixup 1: f32 recompute via hi+lo tables (err ~3e-5), re-flag at EPS2 ----
__global__ __launch_bounds__(256) void fixup1_f32_kernel(
    const int* __restrict__ ei, const float* __restrict__ ef,
    const float* __restrict__ W1, const float* __restrict__ W2,
    const float* __restrict__ b2, const float* __restrict__ W3, const float* __restrict__ b3,
    const unsigned short* __restrict__ Uhi, const unsigned short* __restrict__ Ulo,
    const unsigned short* __restrict__ Vhi, const unsigned short* __restrict__ Vlo,
    const int* __restrict__ counter, const int* __restrict__ list, int cap,
    int* __restrict__ counter2, int* __restrict__ list2, int cap2,
    float* __restrict__ out)
{
    __shared__ float W1e[64][32];   // 8KB: W1[:,128:160]
    __shared__ float W2s[32][64];   // 8KB
    __shared__ float fh[4][HID];
    const int wave = threadIdx.x >> 6, lane = threadIdx.x & 63;
    for (int i = threadIdx.x; i < 64*32; i += blockDim.x)
        W1e[i >> 5][i & 31] = W1[(size_t)(i >> 5)*D_IN + 128 + (i & 31)];
    for (int i = threadIdx.x; i < 32*64; i += blockDim.x)
        W2s[i >> 6][i & 63] = W2[i];
    __syncthreads();

    const int nwaves = (gridDim.x * blockDim.x) >> 6;
    const int wid = (blockIdx.x * blockDim.x + threadIdx.x) >> 6;
    int n = counter[0]; if (n > cap) n = cap;
    const int is64 = (ei[1]==0)&(ei[3]==0)&(ei[5]==0)&(ei[7]==0);

    for (int i = wid; i < n; i += nwaves) {
        const int e = list[i];
        int si, ti;
        if (is64) { si = ei[(size_t)2*e]; ti = ei[(size_t)2*(NE + (long long)e)]; }
        else      { si = ei[e];           ti = ei[NE + (size_t)e]; }
        const float u = bf16_tof(Uhi[(size_t)si*64 + lane]) + bf16_tof(Ulo[(size_t)si*64 + lane]);
        const float v = bf16_tof(Vhi[(size_t)ti*64 + lane]) + bf16_tof(Vlo[(size_t)ti*64 + lane]);
        const float* ep = ef + (size_t)e * D_EDGE;
        float p0 = u + v, p1 = 0.f, p2 = 0.f, p3 = 0.f;
        #pragma unroll
        for (int k = 0; k < 32; k += 4) {
            p0 = fmaf(ep[k+0], W1e[lane][k+0], p0);
            p1 = fmaf(ep[k+1], W1e[lane][k+1], p1);
            p2 = fmaf(ep[k+2], W1e[lane][k+2], p2);
            p3 = fmaf(ep[k+3], W1e[lane][k+3], p3);
        }
        fh[wave][lane] = fmaxf((p0 + p1) + (p2 + p3), 0.f);
        asm volatile("s_waitcnt lgkmcnt(0)" ::: "memory");

        float tsum = 0.f;
        if (lane < H2C) {
            float h0 = b2[lane], h1 = 0.f, h2 = 0.f, h3 = 0.f;
            #pragma unroll
            for (int j = 0; j < 64; j += 4) {
                h0 = fmaf(fh[wave][j+0], W2s[lane][j+0], h0);
                h1 = fmaf(fh[wave][j+1], W2s[lane][j+1], h1);
                h2 = fmaf(fh[wave][j+2], W2s[lane][j+2], h2);
                h3 = fmaf(fh[wave][j+3], W2s[lane][j+3], h3);
            }
            tsum = fmaxf((h0 + h1) + (h2 + h3), 0.f) * W3[lane];
        }
        #pragma unroll
        for (int off = 1; off < 32; off <<= 1) tsum += __shfl_xor(tsum, off, 32);
        if (lane == 0) {
            const float lg = tsum + b3[0];
            const float sc = 1.0f / (1.0f + expf(-lg));
            out[e] = sc;
            out[NE + (size_t)e] = (sc >= 0.5f) ? 1.0f : 0.0f;
            if (fabsf(lg) < EPS2) {
                const int idx = atomicAdd(counter2, 1);
                if (idx < cap2) list2[idx] = e;
            }
        }
        asm volatile("s_waitcnt lgkmcnt(0)" ::: "memory");
    }
}

// ---- Fixup 2: f64 exact (proven), over list2 ----
__global__ __launch_bounds__(256) void fixup_wave_f64_kernel(
    const float* __restrict__ nf, const int* __restrict__ ei,
    const float* __restrict__ ef,
    const float* __restrict__ W1, const float* __restrict__ b1,
    const float* __restrict__ W2, const float* __restrict__ b2,
    const float* __restrict__ W3, const float* __restrict__ b3,
    const int* __restrict__ counter, const int* __restrict__ list, int cap,
    float* __restrict__ out)
{
    __shared__ double fh[4][HID];
    const int wave = threadIdx.x >> 6, lane = threadIdx.x & 63;
    const int nwaves = (gridDim.x * blockDim.x) >> 6;
    const int wid = (blockIdx.x * blockDim.x + threadIdx.x) >> 6;
    int n = counter[0]; if (n > cap) n = cap;
    const int is64 = (ei[1]==0)&(ei[3]==0)&(ei[5]==0)&(ei[7]==0);

    for (int i = wid; i < n; i += nwaves) {
        const int e = list[i];
        int si, ti;
        if (is64) { si = ei[(size_t)2*e]; ti = ei[(size_t)2*(NE + (long long)e)]; }
        else      { si = ei[e];           ti = ei[NE + (size_t)e]; }
        const float* sp = nf + (size_t)si * D_NODE;
        const float* tp = nf + (size_t)ti * D_NODE;
        const float* ep = ef + (size_t)e * D_EDGE;

        double a0 = (double)b1[lane], a1 = 0.0, a2 = 0.0, a3 = 0.0;
        const float* w1r = W1 + (size_t)lane * D_IN;
        #pragma unroll 4
        for (int k = 0; k < 64; k += 4) {
            a0 = fma((double)sp[k+0], (double)w1r[k+0], a0);
            a1 = fma((double)sp[k+1], (double)w1r[k+1], a1);
            a2 = fma((double)sp[k+2], (double)w1r[k+2], a2);
            a3 = fma((double)sp[k+3], (double)w1r[k+3], a3);
        }
        #pragma unroll 4
        for (int k = 0; k < 64; k += 4) {
            a0 = fma((double)tp[k+0], (double)w1r[64+k+0], a0);
            a1 = fma((double)tp[k+1], (double)w1r[64+k+1], a1);
            a2 = fma((double)tp[k+2], (double)w1r[64+k+2], a2);
            a3 = fma((double)tp[k+3], (double)w1r[64+k+3], a3);
        }
        #pragma unroll 4
        for (int k = 0; k < 32; k += 4) {
            a0 = fma((double)ep[k+0], (double)w1r[128+k+0], a0);
            a1 = fma((double)ep[k+1], (double)w1r[128+k+1], a1);
            a2 = fma((double)ep[k+2], (double)w1r[128+k+2], a2);
            a3 = fma((double)ep[k+3], (double)w1r[128+k+3], a3);
        }
        fh[wave][lane] = fmax((a0 + a1) + (a2 + a3), 0.0);
        asm volatile("s_waitcnt lgkmcnt(0)" ::: "memory");

        double tsum = 0.0;
        if (lane < H2C) {
            double h0 = (double)b2[lane], h1 = 0.0, h2 = 0.0, h3 = 0.0;
            const float* w2r = W2 + (size_t)lane * HID;
            #pragma unroll 4
            for (int j = 0; j < 64; j += 4) {
                h0 = fma(fh[wave][j+0], (double)w2r[j+0], h0);
                h1 = fma(fh[wave][j+1], (double)w2r[j+1], h1);
                h2 = fma(fh[wave][j+2], (double)w2r[j+2], h2);
                h3 = fma(fh[wave][j+3], (double)w2r[j+3], h3);
            }
            tsum = fmax((h0 + h1) + (h2 + h3), 0.0) * (double)W3[lane];
        }
        #pragma unroll
        for (int off = 1; off < 32; off <<= 1) tsum += __shfl_xor(tsum, off, 32);
        if (lane == 0) {
            const double logit = tsum + (double)b3[0];
            const float sc = (float)(1.0 / (1.0 + exp(-logit)));
            out[e] = sc;
            out[NE + (size_t)e] = (sc >= 0.5f) ? 1.0f : 0.0f;
        }
        asm volatile("s_waitcnt lgkmcnt(0)" ::: "memory");
    }
}

// ---------- Fallback (tiny ws): proven f32 VALU path ----------
__global__ void zero_counter_kernel(int* __restrict__ c) {
    if (blockIdx.x == 0 && threadIdx.x == 0) c[0] = 0;
}

__global__ __launch_bounds__(256, 4) void edge_mlp_f32_kernel(
    const float* __restrict__ nf, const int* __restrict__ ei,
    const float* __restrict__ ef,
    const float* __restrict__ W1, const float* __restrict__ b1,
    const float* __restrict__ W2, const float* __restrict__ b2,
    const float* __restrict__ W3, const float* __restrict__ b3,
    int* __restrict__ counter, int* __restrict__ list, int cap,
    float* __restrict__ out)
{
    const int e = blockIdx.x * blockDim.x + threadIdx.x;
    if (e >= NE) return;
    const int is64 = (ei[1]==0)&(ei[3]==0)&(ei[5]==0)&(ei[7]==0);
    int si, ti;
    if (is64) { si = ei[2*(size_t)e]; ti = ei[2*((size_t)NE + e)]; }
    else      { si = ei[e];           ti = ei[NE + e]; }
    const float* srcp = nf + (size_t)si * D_NODE;
    const float* tgtp = nf + (size_t)ti * D_NODE;
    const float* efp  = ef + (size_t)e  * D_EDGE;

    float acc[HID];
    #pragma unroll
    for (int j = 0; j < HID; ++j) acc[j] = b1[j];
    #pragma unroll 1
    for (int kc = 0; kc < D_IN / 16; ++kc) {
        const float* base = (kc < 4) ? (srcp + kc * 16)
                          : (kc < 8) ? (tgtp + (kc - 4) * 16)
                                     : (efp  + (kc - 8) * 16);
        float c[16];
        #pragma unroll
        for (int q = 0; q < 4; ++q) {
            const float4 v = *reinterpret_cast<const float4*>(base + q * 4);
            c[q*4+0]=v.x; c[q*4+1]=v.y; c[q*4+2]=v.z; c[q*4+3]=v.w;
        }
        #pragma unroll
        for (int j = 0; j < HID; ++j)
            #pragma unroll
            for (int q = 0; q < 16; ++q)
                acc[j] = fmaf(c[q], W1[j*D_IN + kc*16 + q], acc[j]);
    }
    #pragma unroll
    for (int j = 0; j < HID; ++j) acc[j] = fmaxf(acc[j], 0.0f);

    float logit = b3[0];
    #pragma unroll 1
    for (int jj = 0; jj < H2C; ++jj) {
        float h = b2[jj];
        #pragma unroll
        for (int j = 0; j < HID; ++j) h = fmaf(acc[j], W2[jj*HID + j], h);
        logit = fmaf(fmaxf(h, 0.0f), W3[jj], logit);
    }
    const float score = 1.0f / (1.0f + expf(-logit));
    out[e] = score;
    out[(size_t)NE + e] = (score >= 0.5f) ? 1.0f : 0.0f;
    if (fabsf(logit) < EPS2) {
        const int idx = atomicAdd(counter, 1);
        if (idx < cap) list[idx] = e;
    }
}

extern "C" void kernel_launch(void* const* d_in, const int* in_sizes, int n_in,
                              void* d_out, int out_size, void* d_ws, size_t ws_size,
                              hipStream_t stream) {
    const float* nf = (const float*)d_in[0];
    const int*   ei = (const int*)  d_in[1];
    const float* ef = (const float*)d_in[2];
    const float* W1 = (const float*)d_in[3];
    const float* b1 = (const float*)d_in[4];
    const float* W2 = (const float*)d_in[5];
    const float* b2 = (const float*)d_in[6];
    const float* W3 = (const float*)d_in[7];
    const float* b3 = (const float*)d_in[8];
    float* out = (float*)d_out;
    unsigned char* ws = (unsigned char*)d_ws;
    int* counter  = (int*)ws;
    int* counter2 = (int*)(ws + 4);

    if (ws_size >= (size_t)WS_V7_MIN) {
        unsigned short* Uhi = (unsigned short*)(ws + WS_UHI);
        unsigned short* Ulo = (unsigned short*)(ws + WS_ULO);
        unsigned short* Vhi = (unsigned short*)(ws + WS_VHI);
        unsigned short* Vlo = (unsigned short*)(ws + WS_VLO);
        int* list1 = (int*)(ws + WS_L1_OFF);
        int* list2 = (int*)(ws + WS_L2_OFF);
        hipLaunchKernelGGL(prep_uv_kernel, dim3((N_NODES + 31) / 32), dim3(256), 0, stream,
                           nf, W1, b1, Uhi, Ulo, Vhi, Vlo);
        hipLaunchKernelGGL(prep_pack_v7, dim3(2), dim3(256), 0, stream, W1, W2, ws);
        hipLaunchKernelGGL(edge_mlp_v7_kernel, dim3((NE + 127) / 128), dim3(256), 0, stream,
                           ei, ef, b2, W3, b3,
                           (const unsigned short*)(ws + WS_A1_OFF),
                           (const unsigned short*)(ws + WS_A2_OFF),
                           Uhi, Vhi, counter, list1, L1_CAP, out);
        hipLaunchKernelGGL(fixup1_f32_kernel, dim3(1024), dim3(256), 0, stream,
                           ei, ef, W1, W2, b2, W3, b3,
                           Uhi, Ulo, Vhi, Vlo,
                           counter, list1, L1_CAP, counter2, list2, L2_CAP, out);
        hipLaunchKernelGGL(fixup_wave_f64_kernel, dim3(256), dim3(256), 0, stream,
                           nf, ei, ef, W1, b1, W2, b2, W3, b3,
                           counter2, list2, L2_CAP, out);
    } else {
        long long cap_ll = ((long long)ws_size - 16) / 4;
        const int cap = (int)(cap_ll < 0 ? 0 : (cap_ll > NE ? NE : cap_ll));
        int* slist = (int*)(ws + 16);
        hipLaunchKernelGGL(zero_counter_kernel, dim3(1), dim3(64), 0, stream, counter);
        hipLaunchKernelGGL(edge_mlp_f32_kernel, dim3((NE + 255)/256), dim3(256), 0, stream,
                           nf, ei, ef, W1, b1, W2, b2, W3, b3, counter, slist, cap, out);
        hipLaunchKernelGGL(fixup_wave_f64_kernel, dim3(256), dim3(256), 0, stream,
                           nf, ei, ef, W1, b1, W2, b2, W3, b3, counter, slist, cap, out);
    }
}

// Round 8
// 470.789 us; speedup vs baseline: 6.2178x; 3.4551x over previous
//
#include <hip/hip_runtime.h>
#include <math.h>

#define N_NODES 100000
#define NE 1000000
#define D_NODE 64
#define D_EDGE 32
#define HID 64
#define H2C 32
#define D_IN 160
#define NTILES (NE / 16)        // 62500
#define EPS1 5e-3f              // fp16-table error bound (logit std ~1.4e-4)
#define EPS2 1e-3f              // f32-path error bound (validated rounds 3-7)

typedef __attribute__((ext_vector_type(8))) short short8;   // 8 bf16 or fp16
typedef __attribute__((ext_vector_type(4))) float f32x4;

// ws byte layout (v8 path):
//  [0,4) counter2   [4,16) pad
//  [16, +8192)        a1 frags (W1e bf16 hi|lo)
//  [8208, +8192)      a2 frags (W2 bf16 hi|lo)
//  [16640, +12.8MB)   Uhi fp16 [100K][64]   (= nf@W1s^T + b1)
//  ...                Ulo, Vhi, Vlo fp16
//  [51216640,+125000) per-tile 16-bit flag masks
//  [51341648,+256KB)  list2
#define WS_A1_OFF 16
#define WS_A2_OFF 8208
#define WS_UHI 16640
#define TBL_BYTES (N_NODES * HID * 2)          // 12,800,000
#define WS_ULO (WS_UHI + TBL_BYTES)
#define WS_VHI (WS_ULO + TBL_BYTES)
#define WS_VLO (WS_VHI + TBL_BYTES)
#define WS_MASK (WS_VLO + TBL_BYTES)           // 51,216,640
#define WS_L2O  (WS_MASK + NTILES * 2 + 48)    // 51,341,688 -> align 8 below
#define WS_L2OA ((WS_L2O + 7) & ~7)
#define L2_CAP 65536
#define WS_V8_MIN (WS_L2OA + L2_CAP * 4)       // ~51.6 MB (< 53.08 MB proven)

__device__ __forceinline__ unsigned short bf16_rne(float x) {
    unsigned int u = __float_as_uint(x);
    u += 0x7fffu + ((u >> 16) & 1u);
    return (unsigned short)(u >> 16);
}
__device__ __forceinline__ float bf16_tof(unsigned short h) {
    return __uint_as_float(((unsigned int)h) << 16);
}
__device__ __forceinline__ float h2f(unsigned short h) {
    _Float16 x = *reinterpret_cast<const _Float16*>(&h);
    return (float)x;
}
__device__ __forceinline__ unsigned short f2h(float f) {
    _Float16 x = (_Float16)f;   // RNE
    return *reinterpret_cast<const unsigned short*>(&x);
}
__device__ __forceinline__ void split8(const float* xs, short8& hi, short8& lo) {
    #pragma unroll
    for (int i = 0; i < 8; ++i) {
        unsigned short h = bf16_rne(xs[i]);
        float fh = bf16_tof(h);
        unsigned short l = bf16_rne(xs[i] - fh);
        hi[i] = (short)h;
        lo[i] = (short)l;
    }
}

// ---- Prep 1: per-node U = nf@W1s^T + b1, V = nf@W1t^T (f32), stored fp16 hi+lo ----
__global__ void prep_uv_v8(const float* __restrict__ nf, const float* __restrict__ W1,
                           const float* __restrict__ b1,
                           unsigned short* __restrict__ Uhi, unsigned short* __restrict__ Ulo,
                           unsigned short* __restrict__ Vhi, unsigned short* __restrict__ Vlo)
{
    const int wave = threadIdx.x >> 6, lane = threadIdx.x & 63;  // lane = hidden j
    float w[128];
    #pragma unroll
    for (int q = 0; q < 32; ++q) {
        const float4 t = *(const float4*)(W1 + lane * D_IN + q * 4);
        w[q*4+0]=t.x; w[q*4+1]=t.y; w[q*4+2]=t.z; w[q*4+3]=t.w;
    }
    const float bj = b1[lane];
    const int node0 = (blockIdx.x * 4 + wave) * 8;
    #pragma unroll 1
    for (int ni = 0; ni < 8; ++ni) {
        const int node = node0 + ni;
        if (node >= N_NODES) return;
        const float xj = nf[(size_t)node * 64 + lane];
        float u = bj, v = 0.f;
        #pragma unroll
        for (int k = 0; k < 64; ++k) {
            const float xk = __shfl(xj, k, 64);
            u = fmaf(xk, w[k], u);
            v = fmaf(xk, w[64 + k], v);
        }
        const unsigned short uh = f2h(u), vh = f2h(v);
        Uhi[(size_t)node*64 + lane] = uh;
        Ulo[(size_t)node*64 + lane] = f2h(u - h2f(uh));
        Vhi[(size_t)node*64 + lane] = vh;
        Vlo[(size_t)node*64 + lane] = f2h(v - h2f(vh));
    }
}

// ---- Prep 2: pack W1e / W2 MFMA fragments (bf16 hi|lo), zero counter2 ----
__global__ void prep_pack_v8(const float* __restrict__ W1, const float* __restrict__ W2,
                             unsigned char* __restrict__ ws)
{
    const int t = blockIdx.x * blockDim.x + threadIdx.x;
    if (t == 0) { *(int*)ws = 0; }
    unsigned short* a1 = (unsigned short*)(ws + WS_A1_OFF);
    unsigned short* a2 = (unsigned short*)(ws + WS_A2_OFF);
    for (int task = t; task < 512; task += gridDim.x * blockDim.x) {
        const int isA2 = task >= 256;
        const int tt = task & 255;
        const int f = tt >> 6, l = tt & 63;
        const int l15 = l & 15, kg = l >> 4;
        const float* src;
        unsigned short* dst;
        if (!isA2) {
            src = W1 + (size_t)(f*16 + l15)*D_IN + 128 + kg*8;
            dst = a1 + ((size_t)f*64 + l)*16;
        } else {
            const int nn2 = f >> 1, kk = f & 1;
            src = W2 + (size_t)(nn2*16 + l15)*HID + kk*32 + kg*8;
            dst = a2 + ((size_t)f*64 + l)*16;
        }
        #pragma unroll
        for (int i = 0; i < 8; ++i) {
            const float wv = src[i];
            const unsigned short h = bf16_rne(wv);
            dst[i] = h;
            dst[8+i] = bf16_rne(wv - bf16_tof(h));
        }
    }
}

// ---- Main v8: identical to proven v7 structure; fp16 tables; NO ATOMICS ----
__global__ __launch_bounds__(256) void edge_mlp_v8_kernel(
    const int* __restrict__ ei, const float* __restrict__ ef,
    const float* __restrict__ b2, const float* __restrict__ W3, const float* __restrict__ b3,
    const unsigned short* __restrict__ a1p, const unsigned short* __restrict__ a2p,
    const unsigned short* __restrict__ Uhi, const unsigned short* __restrict__ Vhi,
    unsigned short* __restrict__ maskbuf,
    float* __restrict__ out)
{
    __shared__ __attribute__((aligned(16))) float Hs[4][16][68];
    const int wave = threadIdx.x >> 6, lane = threadIdx.x & 63;
    const int l15 = lane & 15, kg = lane >> 4;
    const long long e0 = (long long)blockIdx.x * 128 + wave * 32;

    const int is64 = (ei[1]==0)&(ei[3]==0)&(ei[5]==0)&(ei[7]==0);

    int si[2], ti[2];
    const float* efpp[2];
    #pragma unroll
    for (int t = 0; t < 2; ++t) {
        long long e = e0 + t * 16 + l15;
        if (e >= NE) e = NE - 1;
        if (is64) { si[t] = ei[(size_t)(2*e)]; ti[t] = ei[(size_t)(2*(NE+e))]; }
        else      { si[t] = ei[(size_t)e];     ti[t] = ei[(size_t)(NE+e)]; }
        efpp[t] = ef + (size_t)e * D_EDGE;
    }
    float4 efv[2][2];
    #pragma unroll
    for (int t = 0; t < 2; ++t) {
        efv[t][0] = *(const float4*)(efpp[t] + kg*8);
        efv[t][1] = *(const float4*)(efpp[t] + kg*8 + 4);
    }
    short8 uh[2][2], vh[2][2];
    #pragma unroll
    for (int t = 0; t < 2; ++t)
        #pragma unroll
        for (int kk = 0; kk < 2; ++kk) {
            uh[t][kk] = *(const short8*)(Uhi + (size_t)si[t]*64 + kk*32 + kg*8);
            vh[t][kk] = *(const short8*)(Vhi + (size_t)ti[t]*64 + kk*32 + kg*8);
        }

    const f32x4 z4 = {0.f,0.f,0.f,0.f};
    f32x4 acc1[2][4];
    #pragma unroll
    for (int t = 0; t < 2; ++t) {
        float xs[8] = {efv[t][0].x,efv[t][0].y,efv[t][0].z,efv[t][0].w,
                       efv[t][1].x,efv[t][1].y,efv[t][1].z,efv[t][1].w};
        short8 ahi, alo;
        split8(xs, ahi, alo);
        #pragma unroll
        for (int nn = 0; nn < 4; ++nn) {
            const unsigned short* fp = a1p + ((size_t)nn*64 + lane)*16;
            const short8 bhi = *(const short8*)fp;
            const short8 blo = *(const short8*)(fp + 8);
            f32x4 a = z4;
            a = __builtin_amdgcn_mfma_f32_16x16x32_bf16(ahi, bhi, a, 0,0,0);
            a = __builtin_amdgcn_mfma_f32_16x16x32_bf16(ahi, blo, a, 0,0,0);
            a = __builtin_amdgcn_mfma_f32_16x16x32_bf16(alo, bhi, a, 0,0,0);
            acc1[t][nn] = a;
        }
    }

    const float b2a = b2[l15], b2b = b2[16 + l15];
    const float w3a = W3[l15], w3b = W3[16 + l15];
    const float b3s = b3[0];

    #pragma unroll
    for (int t = 0; t < 2; ++t) {
        #pragma unroll
        for (int nn = 0; nn < 4; ++nn)
            #pragma unroll
            for (int r = 0; r < 4; ++r)
                Hs[wave][kg*4 + r][nn*16 + l15] = acc1[t][nn][r];
        asm volatile("s_waitcnt lgkmcnt(0)" ::: "memory");

        f32x4 acc2[2] = {z4, z4};
        #pragma unroll
        for (int kk = 0; kk < 2; ++kk) {
            const float* hp = &Hs[wave][l15][kk*32 + kg*8];
            float xs[8];
            #pragma unroll
            for (int i = 0; i < 8; ++i)
                xs[i] = fmaxf(hp[i] + h2f((unsigned short)uh[t][kk][i])
                                    + h2f((unsigned short)vh[t][kk][i]), 0.f);
            short8 a2hi, a2lo;
            split8(xs, a2hi, a2lo);
            #pragma unroll
            for (int nn = 0; nn < 2; ++nn) {
                const unsigned short* fp = a2p + ((size_t)(nn*2+kk)*64 + lane)*16;
                const short8 bhi = *(const short8*)fp;
                const short8 blo = *(const short8*)(fp + 8);
                acc2[nn] = __builtin_amdgcn_mfma_f32_16x16x32_bf16(a2hi, bhi, acc2[nn],0,0,0);
                acc2[nn] = __builtin_amdgcn_mfma_f32_16x16x32_bf16(a2hi, blo, acc2[nn],0,0,0);
                acc2[nn] = __builtin_amdgcn_mfma_f32_16x16x32_bf16(a2lo, bhi, acc2[nn],0,0,0);
            }
        }
        asm volatile("s_waitcnt lgkmcnt(0)" ::: "memory");

        float vv[4];
        #pragma unroll
        for (int r = 0; r < 4; ++r) {
            float x = fmaxf(acc2[0][r] + b2a, 0.f) * w3a + fmaxf(acc2[1][r] + b2b, 0.f) * w3b;
            #pragma unroll
            for (int off = 1; off < 16; off <<= 1) x += __shfl_xor(x, off, 16);
            vv[r] = x + b3s;
        }
        float lg = 0.f;
        bool valid = false;
        #pragma unroll 1
        for (int dummy = 0; dummy < 1; ++dummy) { }
        long long e = 0;
        if (l15 < 4) {
            lg = (l15 == 0) ? vv[0] : (l15 == 1) ? vv[1] : (l15 == 2) ? vv[2] : vv[3];
            e = e0 + t * 16 + kg * 4 + l15;
            valid = (e < NE);
            if (valid) {
                const float sc = 1.0f / (1.0f + expf(-lg));
                out[e] = sc;
                out[NE + e] = (sc >= 0.5f) ? 1.0f : 0.0f;
            }
        }
        // Zero-atomic flagging: one ushort mask per 16-edge tile.
        const bool flag = valid && (fabsf(lg) < EPS1);
        const unsigned long long m = __ballot(flag);
        // edge-in-tile bit = kg*4+l15; ballot bit = kg*16+l15 (l15<4)
        const unsigned int mask16 = (unsigned int)( (m & 0xFull)
                                                  | ((m >> 12) & 0xF0ull)
                                                  | ((m >> 24) & 0xF00ull)
                                                  | ((m >> 36) & 0xF000ull) );
        const long long tile = (e0 + t * 16) >> 4;
        if (lane == 0 && tile < NTILES) maskbuf[tile] = (unsigned short)mask16;
    }
}

// ---- Fixup 1: mask-driven wave-per-tile f32 recompute (fp16 hi+lo, err ~1e-6) ----
__global__ __launch_bounds__(256) void fixup1_v8(
    const int* __restrict__ ei, const float* __restrict__ ef,
    const float* __restrict__ W1, const float* __restrict__ W2,
    const float* __restrict__ b2, const float* __restrict__ W3, const float* __restrict__ b3,
    const unsigned short* __restrict__ Uhi, const unsigned short* __restrict__ Ulo,
    const unsigned short* __restrict__ Vhi, const unsigned short* __restrict__ Vlo,
    const unsigned short* __restrict__ maskbuf,
    int* __restrict__ counter2, int* __restrict__ list2, int cap2,
    float* __restrict__ out)
{
    __shared__ float W1e[64][33];
    __shared__ float W2s[32][65];
    __shared__ float fh[4][HID];
    const int wave = threadIdx.x >> 6, lane = threadIdx.x & 63;
    for (int i = threadIdx.x; i < 64*32; i += blockDim.x)
        W1e[i >> 5][i & 31] = W1[(size_t)(i >> 5)*D_IN + 128 + (i & 31)];
    for (int i = threadIdx.x; i < 32*64; i += blockDim.x)
        W2s[i >> 6][i & 63] = W2[i];
    __syncthreads();

    const float b2l = (lane < H2C) ? b2[lane] : 0.f;
    const float w3l = (lane < H2C) ? W3[lane] : 0.f;
    const float b3s = b3[0];
    const int nwaves = (gridDim.x * blockDim.x) >> 6;
    const int wid = (blockIdx.x * blockDim.x + threadIdx.x) >> 6;
    const int is64 = (ei[1]==0)&(ei[3]==0)&(ei[5]==0)&(ei[7]==0);

    for (int tile = wid; tile < NTILES; tile += nwaves) {
        unsigned int mask = maskbuf[tile];
        while (mask) {
            const int b = __ffs(mask) - 1;
            mask &= mask - 1;
            const int e = tile * 16 + b;
            int si, ti;
            if (is64) { si = ei[(size_t)2*e]; ti = ei[(size_t)2*(NE + (long long)e)]; }
            else      { si = ei[e];           ti = ei[NE + (size_t)e]; }
            const float u = h2f(Uhi[(size_t)si*64 + lane]) + h2f(Ulo[(size_t)si*64 + lane]);
            const float v = h2f(Vhi[(size_t)ti*64 + lane]) + h2f(Vlo[(size_t)ti*64 + lane]);
            const float* ep = ef + (size_t)e * D_EDGE;
            float p0 = u + v, p1 = 0.f, p2 = 0.f, p3 = 0.f;
            #pragma unroll
            for (int k = 0; k < 32; k += 4) {
                p0 = fmaf(ep[k+0], W1e[lane][k+0], p0);
                p1 = fmaf(ep[k+1], W1e[lane][k+1], p1);
                p2 = fmaf(ep[k+2], W1e[lane][k+2], p2);
                p3 = fmaf(ep[k+3], W1e[lane][k+3], p3);
            }
            fh[wave][lane] = fmaxf((p0 + p1) + (p2 + p3), 0.f);
            asm volatile("s_waitcnt lgkmcnt(0)" ::: "memory");

            float tsum = 0.f;
            if (lane < H2C) {
                float h0 = b2l, h1 = 0.f, h2 = 0.f, h3 = 0.f;
                #pragma unroll
                for (int j = 0; j < 64; j += 4) {
                    h0 = fmaf(fh[wave][j+0], W2s[lane][j+0], h0);
                    h1 = fmaf(fh[wave][j+1], W2s[lane][j+1], h1);
                    h2 = fmaf(fh[wave][j+2], W2s[lane][j+2], h2);
                    h3 = fmaf(fh[wave][j+3], W2s[lane][j+3], h3);
                }
                tsum = fmaxf((h0 + h1) + (h2 + h3), 0.f) * w3l;
            }
            #pragma unroll
            for (int off = 1; off < 32; off <<= 1) tsum += __shfl_xor(tsum, off, 32);
            if (lane == 0) {
                const float lg = tsum + b3s;
                const float sc = 1.0f / (1.0f + expf(-lg));
                out[e] = sc;
                out[NE + (size_t)e] = (sc >= 0.5f) ? 1.0f : 0.0f;
                if (fabsf(lg) < EPS2) {
                    const int idx = atomicAdd(counter2, 1);
                    if (idx < cap2) list2[idx] = e;
                }
            }
            asm volatile("s_waitcnt lgkmcnt(0)" ::: "memory");
        }
    }
}

// ---- Fixup 2: f64 exact (proven) over list2 ----
__global__ __launch_bounds__(256) void fixup_wave_f64_kernel(
    const float* __restrict__ nf, const int* __restrict__ ei,
    const float* __restrict__ ef,
    const float* __restrict__ W1, const float* __restrict__ b1,
    const float* __restrict__ W2, const float* __restrict__ b2,
    const float* __restrict__ W3, const float* __restrict__ b3,
    const int* __restrict__ counter, const int* __restrict__ list, int cap,
    float* __restrict__ out)
{
    __shared__ double fh[4][HID];
    const int wave = threadIdx.x >> 6, lane = threadIdx.x & 63;
    const int nwaves = (gridDim.x * blockDim.x) >> 6;
    const int wid = (blockIdx.x * blockDim.x + threadIdx.x) >> 6;
    int n = counter[0]; if (n > cap) n = cap;
    const int is64 = (ei[1]==0)&(ei[3]==0)&(ei[5]==0)&(ei[7]==0);

    for (int i = wid; i < n; i += nwaves) {
        const int e = list[i];
        int si, ti;
        if (is64) { si = ei[(size_t)2*e]; ti = ei[(size_t)2*(NE + (long long)e)]; }
        else      { si = ei[e];           ti = ei[NE + (size_t)e]; }
        const float* sp = nf + (size_t)si * D_NODE;
        const float* tp = nf + (size_t)ti * D_NODE;
        const float* ep = ef + (size_t)e * D_EDGE;

        double a0 = (double)b1[lane], a1 = 0.0, a2 = 0.0, a3 = 0.0;
        const float* w1r = W1 + (size_t)lane * D_IN;
        #pragma unroll 4
        for (int k = 0; k < 64; k += 4) {
            a0 = fma((double)sp[k+0], (double)w1r[k+0], a0);
            a1 = fma((double)sp[k+1], (double)w1r[k+1], a1);
            a2 = fma((double)sp[k+2], (double)w1r[k+2], a2);
            a3 = fma((double)sp[k+3], (double)w1r[k+3], a3);
        }
        #pragma unroll 4
        for (int k = 0; k < 64; k += 4) {
            a0 = fma((double)tp[k+0], (double)w1r[64+k+0], a0);
            a1 = fma((double)tp[k+1], (double)w1r[64+k+1], a1);
            a2 = fma((double)tp[k+2], (double)w1r[64+k+2], a2);
            a3 = fma((double)tp[k+3], (double)w1r[64+k+3], a3);
        }
        #pragma unroll 4
        for (int k = 0; k < 32; k += 4) {
            a0 = fma((double)ep[k+0], (double)w1r[128+k+0], a0);
            a1 = fma((double)ep[k+1], (double)w1r[128+k+1], a1);
            a2 = fma((double)ep[k+2], (double)w1r[128+k+2], a2);
            a3 = fma((double)ep[k+3], (double)w1r[128+k+3], a3);
        }
        fh[wave][lane] = fmax((a0 + a1) + (a2 + a3), 0.0);
        asm volatile("s_waitcnt lgkmcnt(0)" ::: "memory");

        double tsum = 0.0;
        if (lane < H2C) {
            double h0 = (double)b2[lane], h1 = 0.0, h2 = 0.0, h3 = 0.0;
            const float* w2r = W2 + (size_t)lane * HID;
            #pragma unroll 4
            for (int j = 0; j < 64; j += 4) {
                h0 = fma(fh[wave][j+0], (double)w2r[j+0], h0);
                h1 = fma(fh[wave][j+1], (double)w2r[j+1], h1);
                h2 = fma(fh[wave][j+2], (double)w2r[j+2], h2);
                h3 = fma(fh[wave][j+3], (double)w2r[j+3], h3);
            }
            tsum = fmax((h0 + h1) + (h2 + h3), 0.0) * (double)W3[lane];
        }
        #pragma unroll
        for (int off = 1; off < 32; off <<= 1) tsum += __shfl_xor(tsum, off, 32);
        if (lane == 0) {
            const double logit = tsum + (double)b3[0];
            const float sc = (float)(1.0 / (1.0 + exp(-logit)));
            out[e] = sc;
            out[NE + (size_t)e] = (sc >= 0.5f) ? 1.0f : 0.0f;
        }
        asm volatile("s_waitcnt lgkmcnt(0)" ::: "memory");
    }
}

// ---------- Fallback (tiny ws): proven f32 VALU path ----------
__global__ void zero_counter_kernel(int* __restrict__ c) {
    if (blockIdx.x == 0 && threadIdx.x == 0) c[0] = 0;
}

__global__ __launch_bounds__(256, 4) void edge_mlp_f32_kernel(
    const float* __restrict__ nf, const int* __restrict__ ei,
    const float* __restrict__ ef,
    const float* __restrict__ W1, const float* __restrict__ b1,
    const float* __restrict__ W2, const float* __restrict__ b2,
    const float* __restrict__ W3, const float* __restrict__ b3,
    int* __restrict__ counter, int* __restrict__ list, int cap,
    float* __restrict__ out)
{
    const int e = blockIdx.x * blockDim.x + threadIdx.x;
    if (e >= NE) return;
    const int is64 = (ei[1]==0)&(ei[3]==0)&(ei[5]==0)&(ei[7]==0);
    int si, ti;
    if (is64) { si = ei[2*(size_t)e]; ti = ei[2*((size_t)NE + e)]; }
    else      { si = ei[e];           ti = ei[NE + e]; }
    const float* srcp = nf + (size_t)si * D_NODE;
    const float* tgtp = nf + (size_t)ti * D_NODE;
    const float* efp  = ef + (size_t)e  * D_EDGE;

    float acc[HID];
    #pragma unroll
    for (int j = 0; j < HID; ++j) acc[j] = b1[j];
    #pragma unroll 1
    for (int kc = 0; kc < D_IN / 16; ++kc) {
        const float* base = (kc < 4) ? (srcp + kc * 16)
                          : (kc < 8) ? (tgtp + (kc - 4) * 16)
                                     : (efp  + (kc - 8) * 16);
        float c[16];
        #pragma unroll
        for (int q = 0; q < 4; ++q) {
            const float4 v = *reinterpret_cast<const float4*>(base + q * 4);
            c[q*4+0]=v.x; c[q*4+1]=v.y; c[q*4+2]=v.z; c[q*4+3]=v.w;
        }
        #pragma unroll
        for (int j = 0; j < HID; ++j)
            #pragma unroll
            for (int q = 0; q < 16; ++q)
                acc[j] = fmaf(c[q], W1[j*D_IN + kc*16 + q], acc[j]);
    }
    #pragma unroll
    for (int j = 0; j < HID; ++j) acc[j] = fmaxf(acc[j], 0.0f);

    float logit = b3[0];
    #pragma unroll 1
    for (int jj = 0; jj < H2C; ++jj) {
        float h = b2[jj];
        #pragma unroll
        for (int j = 0; j < HID; ++j) h = fmaf(acc[j], W2[jj*HID + j], h);
        logit = fmaf(fmaxf(h, 0.0f), W3[jj], logit);
    }
    const float score = 1.0f / (1.0f + expf(-logit));
    out[e] = score;
    out[(size_t)NE + e] = (score >= 0.5f) ? 1.0f : 0.0f;
    if (fabsf(logit) < EPS2) {
        const int idx = atomicAdd(counter, 1);
        if (idx < cap) list[idx] = e;
    }
}

extern "C" void kernel_launch(void* const* d_in, const int* in_sizes, int n_in,
                              void* d_out, int out_size, void* d_ws, size_t ws_size,
                              hipStream_t stream) {
    const float* nf = (const float*)d_in[0];
    const int*   ei = (const int*)  d_in[1];
    const float* ef = (const float*)d_in[2];
    const float* W1 = (const float*)d_in[3];
    const float* b1 = (const float*)d_in[4];
    const float* W2 = (const float*)d_in[5];
    const float* b2 = (const float*)d_in[6];
    const float* W3 = (const float*)d_in[7];
    const float* b3 = (const float*)d_in[8];
    float* out = (float*)d_out;
    unsigned char* ws = (unsigned char*)d_ws;
    int* counter2 = (int*)ws;

    if (ws_size >= (size_t)WS_V8_MIN) {
        unsigned short* Uhi = (unsigned short*)(ws + WS_UHI);
        unsigned short* Ulo = (unsigned short*)(ws + WS_ULO);
        unsigned short* Vhi = (unsigned short*)(ws + WS_VHI);
        unsigned short* Vlo = (unsigned short*)(ws + WS_VLO);
        unsigned short* masks = (unsigned short*)(ws + WS_MASK);
        int* list2 = (int*)(ws + WS_L2OA);
        hipLaunchKernelGGL(prep_uv_v8, dim3((N_NODES + 31) / 32), dim3(256), 0, stream,
                           nf, W1, b1, Uhi, Ulo, Vhi, Vlo);
        hipLaunchKernelGGL(prep_pack_v8, dim3(2), dim3(256), 0, stream, W1, W2, ws);
        hipLaunchKernelGGL(edge_mlp_v8_kernel, dim3((NE + 127) / 128), dim3(256), 0, stream,
                           ei, ef, b2, W3, b3,
                           (const unsigned short*)(ws + WS_A1_OFF),
                           (const unsigned short*)(ws + WS_A2_OFF),
                           Uhi, Vhi, masks, out);
        hipLaunchKernelGGL(fixup1_v8, dim3(2048), dim3(256), 0, stream,
                           ei, ef, W1, W2, b2, W3, b3,
                           Uhi, Ulo, Vhi, Vlo, masks,
                           counter2, list2, L2_CAP, out);
        hipLaunchKernelGGL(fixup_wave_f64_kernel, dim3(256), dim3(256), 0, stream,
                           nf, ei, ef, W1, b1, W2, b2, W3, b3,
                           counter2, list2, L2_CAP, out);
    } else {
        long long cap_ll = ((long long)ws_size - 16) / 4;
        const int cap = (int)(cap_ll < 0 ? 0 : (cap_ll > NE ? NE : cap_ll));
        int* slist = (int*)(ws + 16);
        hipLaunchKernelGGL(zero_counter_kernel, dim3(1), dim3(64), 0, stream, counter2);
        hipLaunchKernelGGL(edge_mlp_f32_kernel, dim3((NE + 255)/256), dim3(256), 0, stream,
                           nf, ei, ef, W1, b1, W2, b2, W3, b3, counter2, slist, cap, out);
        hipLaunchKernelGGL(fixup_wave_f64_kernel, dim3(256), dim3(256), 0, stream,
                           nf, ei, ef, W1, b1, W2, b2, W3, b3, counter2, slist, cap, out);
    }
}

// Round 9
// 416.243 us; speedup vs baseline: 7.0326x; 1.1310x over previous
//
#include <hip/hip_runtime.h>
#include <math.h>

#define N_NODES 100000
#define NE 1000000
#define D_NODE 64
#define D_EDGE 32
#define HID 64
#define H2C 32
#define D_IN 160
#define NTILES (NE / 16)        // 62500
#define EPS1 5e-3f              // fp16-table error bound (validated round 8)
#define EPS2 1e-3f              // f32-path error bound (validated rounds 3-8)

typedef __attribute__((ext_vector_type(8))) short short8;   // 8 bf16 or fp16
typedef __attribute__((ext_vector_type(4))) float f32x4;

// ws byte layout (identical to round 8):
#define WS_A1_OFF 16
#define WS_A2_OFF 8208
#define WS_UHI 16640
#define TBL_BYTES (N_NODES * HID * 2)          // 12,800,000
#define WS_ULO (WS_UHI + TBL_BYTES)
#define WS_VHI (WS_ULO + TBL_BYTES)
#define WS_VLO (WS_VHI + TBL_BYTES)
#define WS_MASK (WS_VLO + TBL_BYTES)           // 51,216,640
#define WS_L2O  (WS_MASK + NTILES * 2 + 48)
#define WS_L2OA ((WS_L2O + 7) & ~7)
#define L2_CAP 65536
#define WS_V8_MIN (WS_L2OA + L2_CAP * 4)       // ~51.6 MB

__device__ __forceinline__ unsigned short bf16_rne(float x) {
    unsigned int u = __float_as_uint(x);
    u += 0x7fffu + ((u >> 16) & 1u);
    return (unsigned short)(u >> 16);
}
__device__ __forceinline__ float bf16_tof(unsigned short h) {
    return __uint_as_float(((unsigned int)h) << 16);
}
__device__ __forceinline__ float h2f(unsigned short h) {
    _Float16 x = *reinterpret_cast<const _Float16*>(&h);
    return (float)x;
}
__device__ __forceinline__ unsigned short f2h(float f) {
    _Float16 x = (_Float16)f;   // RNE
    return *reinterpret_cast<const unsigned short*>(&x);
}
__device__ __forceinline__ void split8(const float* xs, short8& hi, short8& lo) {
    #pragma unroll
    for (int i = 0; i < 8; ++i) {
        unsigned short h = bf16_rne(xs[i]);
        float fh = bf16_tof(h);
        unsigned short l = bf16_rne(xs[i] - fh);
        hi[i] = (short)h;
        lo[i] = (short)l;
    }
}

// ---- Prep 1 (v9): LDS-broadcast node rows; 8 indep FMA accumulators ----
// Block = 256 thr = 4 waves; block handles 32 nodes (100000 = 3125 * 32).
__global__ __launch_bounds__(256) void prep_uv_v9(
    const float* __restrict__ nf, const float* __restrict__ W1,
    const float* __restrict__ b1,
    unsigned short* __restrict__ Uhi, unsigned short* __restrict__ Ulo,
    unsigned short* __restrict__ Vhi, unsigned short* __restrict__ Vlo)
{
    __shared__ __attribute__((aligned(16))) float xs[32 * 64];  // 8 KB
    const int wave = threadIdx.x >> 6, lane = threadIdx.x & 63;  // lane = hidden j

    // Per-lane weights: W1[lane][0:128] (128 VGPR)
    float w[128];
    #pragma unroll
    for (int q = 0; q < 32; ++q) {
        const float4 t = *(const float4*)(W1 + lane * D_IN + q * 4);
        w[q*4+0]=t.x; w[q*4+1]=t.y; w[q*4+2]=t.z; w[q*4+3]=t.w;
    }
    const float bj = b1[lane];

    // Cooperative coalesced load: 32 rows = 512 float4, 2 per thread.
    const int node0 = blockIdx.x * 32;
    {
        const float4* src = (const float4*)(nf + (size_t)node0 * 64);
        float4* dst = (float4*)xs;
        dst[threadIdx.x]       = src[threadIdx.x];
        dst[threadIdx.x + 256] = src[threadIdx.x + 256];
    }
    __syncthreads();

    // Wave w processes nodes w*8 .. w*8+7 via broadcast LDS reads.
    #pragma unroll 1
    for (int ni = 0; ni < 8; ++ni) {
        const int nl = wave * 8 + ni;
        const int node = node0 + nl;
        const float4* xr = (const float4*)(xs + nl * 64);
        float u0 = bj, u1 = 0.f, u2 = 0.f, u3 = 0.f;
        float v0 = 0.f, v1 = 0.f, v2 = 0.f, v3 = 0.f;
        #pragma unroll
        for (int k4 = 0; k4 < 16; ++k4) {
            const float4 x = xr[k4];   // same addr across lanes -> broadcast
            u0 = fmaf(x.x, w[k4*4+0], u0);
            u1 = fmaf(x.y, w[k4*4+1], u1);
            u2 = fmaf(x.z, w[k4*4+2], u2);
            u3 = fmaf(x.w, w[k4*4+3], u3);
            v0 = fmaf(x.x, w[64+k4*4+0], v0);
            v1 = fmaf(x.y, w[64+k4*4+1], v1);
            v2 = fmaf(x.z, w[64+k4*4+2], v2);
            v3 = fmaf(x.w, w[64+k4*4+3], v3);
        }
        const float u = (u0 + u1) + (u2 + u3);
        const float v = (v0 + v1) + (v2 + v3);
        const unsigned short uhv = f2h(u), vhv = f2h(v);
        Uhi[(size_t)node*64 + lane] = uhv;
        Ulo[(size_t)node*64 + lane] = f2h(u - h2f(uhv));
        Vhi[(size_t)node*64 + lane] = vhv;
        Vlo[(size_t)node*64 + lane] = f2h(v - h2f(vhv));
    }
}

// ---- Prep 2: pack W1e / W2 MFMA fragments (bf16 hi|lo), zero counter2 ----
__global__ void prep_pack_v8(const float* __restrict__ W1, const float* __restrict__ W2,
                             unsigned char* __restrict__ ws)
{
    const int t = blockIdx.x * blockDim.x + threadIdx.x;
    if (t == 0) { *(int*)ws = 0; }
    unsigned short* a1 = (unsigned short*)(ws + WS_A1_OFF);
    unsigned short* a2 = (unsigned short*)(ws + WS_A2_OFF);
    for (int task = t; task < 512; task += gridDim.x * blockDim.x) {
        const int isA2 = task >= 256;
        const int tt = task & 255;
        const int f = tt >> 6, l = tt & 63;
        const int l15 = l & 15, kg = l >> 4;
        const float* src;
        unsigned short* dst;
        if (!isA2) {
            src = W1 + (size_t)(f*16 + l15)*D_IN + 128 + kg*8;
            dst = a1 + ((size_t)f*64 + l)*16;
        } else {
            const int nn2 = f >> 1, kk = f & 1;
            src = W2 + (size_t)(nn2*16 + l15)*HID + kk*32 + kg*8;
            dst = a2 + ((size_t)f*64 + l)*16;
        }
        #pragma unroll
        for (int i = 0; i < 8; ++i) {
            const float wv = src[i];
            const unsigned short h = bf16_rne(wv);
            dst[i] = h;
            dst[8+i] = bf16_rne(wv - bf16_tof(h));
        }
    }
}

// ---- Main v8 (unchanged from passing round 8): fp16 tables; NO ATOMICS ----
__global__ __launch_bounds__(256) void edge_mlp_v8_kernel(
    const int* __restrict__ ei, const float* __restrict__ ef,
    const float* __restrict__ b2, const float* __restrict__ W3, const float* __restrict__ b3,
    const unsigned short* __restrict__ a1p, const unsigned short* __restrict__ a2p,
    const unsigned short* __restrict__ Uhi, const unsigned short* __restrict__ Vhi,
    unsigned short* __restrict__ maskbuf,
    float* __restrict__ out)
{
    __shared__ __attribute__((aligned(16))) float Hs[4][16][68];
    const int wave = threadIdx.x >> 6, lane = threadIdx.x & 63;
    const int l15 = lane & 15, kg = lane >> 4;
    const long long e0 = (long long)blockIdx.x * 128 + wave * 32;

    const int is64 = (ei[1]==0)&(ei[3]==0)&(ei[5]==0)&(ei[7]==0);

    int si[2], ti[2];
    const float* efpp[2];
    #pragma unroll
    for (int t = 0; t < 2; ++t) {
        long long e = e0 + t * 16 + l15;
        if (e >= NE) e = NE - 1;
        if (is64) { si[t] = ei[(size_t)(2*e)]; ti[t] = ei[(size_t)(2*(NE+e))]; }
        else      { si[t] = ei[(size_t)e];     ti[t] = ei[(size_t)(NE+e)]; }
        efpp[t] = ef + (size_t)e * D_EDGE;
    }
    float4 efv[2][2];
    #pragma unroll
    for (int t = 0; t < 2; ++t) {
        efv[t][0] = *(const float4*)(efpp[t] + kg*8);
        efv[t][1] = *(const float4*)(efpp[t] + kg*8 + 4);
    }
    short8 uh[2][2], vh[2][2];
    #pragma unroll
    for (int t = 0; t < 2; ++t)
        #pragma unroll
        for (int kk = 0; kk < 2; ++kk) {
            uh[t][kk] = *(const short8*)(Uhi + (size_t)si[t]*64 + kk*32 + kg*8);
            vh[t][kk] = *(const short8*)(Vhi + (size_t)ti[t]*64 + kk*32 + kg*8);
        }

    const f32x4 z4 = {0.f,0.f,0.f,0.f};
    f32x4 acc1[2][4];
    #pragma unroll
    for (int t = 0; t < 2; ++t) {
        float xsl[8] = {efv[t][0].x,efv[t][0].y,efv[t][0].z,efv[t][0].w,
                        efv[t][1].x,efv[t][1].y,efv[t][1].z,efv[t][1].w};
        short8 ahi, alo;
        split8(xsl, ahi, alo);
        #pragma unroll
        for (int nn = 0; nn < 4; ++nn) {
            const unsigned short* fp = a1p + ((size_t)nn*64 + lane)*16;
            const short8 bhi = *(const short8*)fp;
            const short8 blo = *(const short8*)(fp + 8);
            f32x4 a = z4;
            a = __builtin_amdgcn_mfma_f32_16x16x32_bf16(ahi, bhi, a, 0,0,0);
            a = __builtin_amdgcn_mfma_f32_16x16x32_bf16(ahi, blo, a, 0,0,0);
            a = __builtin_amdgcn_mfma_f32_16x16x32_bf16(alo, bhi, a, 0,0,0);
            acc1[t][nn] = a;
        }
    }

    const float b2a = b2[l15], b2b = b2[16 + l15];
    const float w3a = W3[l15], w3b = W3[16 + l15];
    const float b3s = b3[0];

    #pragma unroll
    for (int t = 0; t < 2; ++t) {
        #pragma unroll
        for (int nn = 0; nn < 4; ++nn)
            #pragma unroll
            for (int r = 0; r < 4; ++r)
                Hs[wave][kg*4 + r][nn*16 + l15] = acc1[t][nn][r];
        asm volatile("s_waitcnt lgkmcnt(0)" ::: "memory");

        f32x4 acc2[2] = {z4, z4};
        #pragma unroll
        for (int kk = 0; kk < 2; ++kk) {
            const float* hp = &Hs[wave][l15][kk*32 + kg*8];
            float xsl[8];
            #pragma unroll
            for (int i = 0; i < 8; ++i)
                xsl[i] = fmaxf(hp[i] + h2f((unsigned short)uh[t][kk][i])
                                     + h2f((unsigned short)vh[t][kk][i]), 0.f);
            short8 a2hi, a2lo;
            split8(xsl, a2hi, a2lo);
            #pragma unroll
            for (int nn = 0; nn < 2; ++nn) {
                const unsigned short* fp = a2p + ((size_t)(nn*2+kk)*64 + lane)*16;
                const short8 bhi = *(const short8*)fp;
                const short8 blo = *(const short8*)(fp + 8);
                acc2[nn] = __builtin_amdgcn_mfma_f32_16x16x32_bf16(a2hi, bhi, acc2[nn],0,0,0);
                acc2[nn] = __builtin_amdgcn_mfma_f32_16x16x32_bf16(a2hi, blo, acc2[nn],0,0,0);
                acc2[nn] = __builtin_amdgcn_mfma_f32_16x16x32_bf16(a2lo, bhi, acc2[nn],0,0,0);
            }
        }
        asm volatile("s_waitcnt lgkmcnt(0)" ::: "memory");

        float vv[4];
        #pragma unroll
        for (int r = 0; r < 4; ++r) {
            float x = fmaxf(acc2[0][r] + b2a, 0.f) * w3a + fmaxf(acc2[1][r] + b2b, 0.f) * w3b;
            #pragma unroll
            for (int off = 1; off < 16; off <<= 1) x += __shfl_xor(x, off, 16);
            vv[r] = x + b3s;
        }
        float lg = 0.f;
        bool valid = false;
        long long e = 0;
        if (l15 < 4) {
            lg = (l15 == 0) ? vv[0] : (l15 == 1) ? vv[1] : (l15 == 2) ? vv[2] : vv[3];
            e = e0 + t * 16 + kg * 4 + l15;
            valid = (e < NE);
            if (valid) {
                const float sc = 1.0f / (1.0f + expf(-lg));
                out[e] = sc;
                out[NE + e] = (sc >= 0.5f) ? 1.0f : 0.0f;
            }
        }
        const bool flag = valid && (fabsf(lg) < EPS1);
        const unsigned long long m = __ballot(flag);
        const unsigned int mask16 = (unsigned int)( (m & 0xFull)
                                                  | ((m >> 12) & 0xF0ull)
                                                  | ((m >> 24) & 0xF00ull)
                                                  | ((m >> 36) & 0xF000ull) );
        const long long tile = (e0 + t * 16) >> 4;
        if (lane == 0 && tile < NTILES) maskbuf[tile] = (unsigned short)mask16;
    }
}

// ---- Fixup 1: mask-driven wave-per-tile f32 recompute (fp16 hi+lo) ----
__global__ __launch_bounds__(256) void fixup1_v8(
    const int* __restrict__ ei, const float* __restrict__ ef,
    const float* __restrict__ W1, const float* __restrict__ W2,
    const float* __restrict__ b2, const float* __restrict__ W3, const float* __restrict__ b3,
    const unsigned short* __restrict__ Uhi, const unsigned short* __restrict__ Ulo,
    const unsigned short* __restrict__ Vhi, const unsigned short* __restrict__ Vlo,
    const unsigned short* __restrict__ maskbuf,
    int* __restrict__ counter2, int* __restrict__ list2, int cap2,
    float* __restrict__ out)
{
    __shared__ float W1e[64][33];
    __shared__ float W2s[32][65];
    __shared__ float fh[4][HID];
    const int wave = threadIdx.x >> 6, lane = threadIdx.x & 63;
    for (int i = threadIdx.x; i < 64*32; i += blockDim.x)
        W1e[i >> 5][i & 31] = W1[(size_t)(i >> 5)*D_IN + 128 + (i & 31)];
    for (int i = threadIdx.x; i < 32*64; i += blockDim.x)
        W2s[i >> 6][i & 63] = W2[i];
    __syncthreads();

    const float b2l = (lane < H2C) ? b2[lane] : 0.f;
    const float w3l = (lane < H2C) ? W3[lane] : 0.f;
    const float b3s = b3[0];
    const int nwaves = (gridDim.x * blockDim.x) >> 6;
    const int wid = (blockIdx.x * blockDim.x + threadIdx.x) >> 6;
    const int is64 = (ei[1]==0)&(ei[3]==0)&(ei[5]==0)&(ei[7]==0);

    for (int tile = wid; tile < NTILES; tile += nwaves) {
        unsigned int mask = maskbuf[tile];
        while (mask) {
            const int b = __ffs(mask) - 1;
            mask &= mask - 1;
            const int e = tile * 16 + b;
            int si, ti;
            if (is64) { si = ei[(size_t)2*e]; ti = ei[(size_t)2*(NE + (long long)e)]; }
            else      { si = ei[e];           ti = ei[NE + (size_t)e]; }
            const float u = h2f(Uhi[(size_t)si*64 + lane]) + h2f(Ulo[(size_t)si*64 + lane]);
            const float v = h2f(Vhi[(size_t)ti*64 + lane]) + h2f(Vlo[(size_t)ti*64 + lane]);
            const float* ep = ef + (size_t)e * D_EDGE;
            float p0 = u + v, p1 = 0.f, p2 = 0.f, p3 = 0.f;
            #pragma unroll
            for (int k = 0; k < 32; k += 4) {
                p0 = fmaf(ep[k+0], W1e[lane][k+0], p0);
                p1 = fmaf(ep[k+1], W1e[lane][k+1], p1);
                p2 = fmaf(ep[k+2], W1e[lane][k+2], p2);
                p3 = fmaf(ep[k+3], W1e[lane][k+3], p3);
            }
            fh[wave][lane] = fmaxf((p0 + p1) + (p2 + p3), 0.f);
            asm volatile("s_waitcnt lgkmcnt(0)" ::: "memory");

            float tsum = 0.f;
            if (lane < H2C) {
                float h0 = b2l, h1 = 0.f, h2 = 0.f, h3 = 0.f;
                #pragma unroll
                for (int j = 0; j < 64; j += 4) {
                    h0 = fmaf(fh[wave][j+0], W2s[lane][j+0], h0);
                    h1 = fmaf(fh[wave][j+1], W2s[lane][j+1], h1);
                    h2 = fmaf(fh[wave][j+2], W2s[lane][j+2], h2);
                    h3 = fmaf(fh[wave][j+3], W2s[lane][j+3], h3);
                }
                tsum = fmaxf((h0 + h1) + (h2 + h3), 0.f) * w3l;
            }
            #pragma unroll
            for (int off = 1; off < 32; off <<= 1) tsum += __shfl_xor(tsum, off, 32);
            if (lane == 0) {
                const float lg = tsum + b3s;
                const float sc = 1.0f / (1.0f + expf(-lg));
                out[e] = sc;
                out[NE + (size_t)e] = (sc >= 0.5f) ? 1.0f : 0.0f;
                if (fabsf(lg) < EPS2) {
                    const int idx = atomicAdd(counter2, 1);
                    if (idx < cap2) list2[idx] = e;
                }
            }
            asm volatile("s_waitcnt lgkmcnt(0)" ::: "memory");
        }
    }
}

// ---- Fixup 2: f64 exact (proven) over list2 ----
__global__ __launch_bounds__(256) void fixup_wave_f64_kernel(
    const float* __restrict__ nf, const int* __restrict__ ei,
    const float* __restrict__ ef,
    const float* __restrict__ W1, const float* __restrict__ b1,
    const float* __restrict__ W2, const float* __restrict__ b2,
    const float* __restrict__ W3, const float* __restrict__ b3,
    const int* __restrict__ counter, const int* __restrict__ list, int cap,
    float* __restrict__ out)
{
    __shared__ double fh[4][HID];
    const int wave = threadIdx.x >> 6, lane = threadIdx.x & 63;
    const int nwaves = (gridDim.x * blockDim.x) >> 6;
    const int wid = (blockIdx.x * blockDim.x + threadIdx.x) >> 6;
    int n = counter[0]; if (n > cap) n = cap;
    const int is64 = (ei[1]==0)&(ei[3]==0)&(ei[5]==0)&(ei[7]==0);

    for (int i = wid; i < n; i += nwaves) {
        const int e = list[i];
        int si, ti;
        if (is64) { si = ei[(size_t)2*e]; ti = ei[(size_t)2*(NE + (long long)e)]; }
        else      { si = ei[e];           ti = ei[NE + (size_t)e]; }
        const float* sp = nf + (size_t)si * D_NODE;
        const float* tp = nf + (size_t)ti * D_NODE;
        const float* ep = ef + (size_t)e * D_EDGE;

        double a0 = (double)b1[lane], a1 = 0.0, a2 = 0.0, a3 = 0.0;
        const float* w1r = W1 + (size_t)lane * D_IN;
        #pragma unroll 4
        for (int k = 0; k < 64; k += 4) {
            a0 = fma((double)sp[k+0], (double)w1r[k+0], a0);
            a1 = fma((double)sp[k+1], (double)w1r[k+1], a1);
            a2 = fma((double)sp[k+2], (double)w1r[k+2], a2);
            a3 = fma((double)sp[k+3], (double)w1r[k+3], a3);
        }
        #pragma unroll 4
        for (int k = 0; k < 64; k += 4) {
            a0 = fma((double)tp[k+0], (double)w1r[64+k+0], a0);
            a1 = fma((double)tp[k+1], (double)w1r[64+k+1], a1);
            a2 = fma((double)tp[k+2], (double)w1r[64+k+2], a2);
            a3 = fma((double)tp[k+3], (double)w1r[64+k+3], a3);
        }
        #pragma unroll 4
        for (int k = 0; k < 32; k += 4) {
            a0 = fma((double)ep[k+0], (double)w1r[128+k+0], a0);
            a1 = fma((double)ep[k+1], (double)w1r[128+k+1], a1);
            a2 = fma((double)ep[k+2], (double)w1r[128+k+2], a2);
            a3 = fma((double)ep[k+3], (double)w1r[128+k+3], a3);
        }
        fh[wave][lane] = fmax((a0 + a1) + (a2 + a3), 0.0);
        asm volatile("s_waitcnt lgkmcnt(0)" ::: "memory");

        double tsum = 0.0;
        if (lane < H2C) {
            double h0 = (double)b2[lane], h1 = 0.0, h2 = 0.0, h3 = 0.0;
            const float* w2r = W2 + (size_t)lane * HID;
            #pragma unroll 4
            for (int j = 0; j < 64; j += 4) {
                h0 = fma(fh[wave][j+0], (double)w2r[j+0], h0);
                h1 = fma(fh[wave][j+1], (double)w2r[j+1], h1);
                h2 = fma(fh[wave][j+2], (double)w2r[j+2], h2);
                h3 = fma(fh[wave][j+3], (double)w2r[j+3], h3);
            }
            tsum = fmax((h0 + h1) + (h2 + h3), 0.0) * (double)W3[lane];
        }
        #pragma unroll
        for (int off = 1; off < 32; off <<= 1) tsum += __shfl_xor(tsum, off, 32);
        if (lane == 0) {
            const double logit = tsum + (double)b3[0];
            const float sc = (float)(1.0 / (1.0 + exp(-logit)));
            out[e] = sc;
            out[NE + (size_t)e] = (sc >= 0.5f) ? 1.0f : 0.0f;
        }
        asm volatile("s_waitcnt lgkmcnt(0)" ::: "memory");
    }
}

// ---------- Fallback (tiny ws): proven f32 VALU path ----------
__global__ void zero_counter_kernel(int* __restrict__ c) {
    if (blockIdx.x == 0 && threadIdx.x == 0) c[0] = 0;
}

__global__ __launch_bounds__(256, 4) void edge_mlp_f32_kernel(
    const float* __restrict__ nf, const int* __restrict__ ei,
    const float* __restrict__ ef,
    const float* __restrict__ W1, const float* __restrict__ b1,
    const float* __restrict__ W2, const float* __restrict__ b2,
    const float* __restrict__ W3, const float* __restrict__ b3,
    int* __restrict__ counter, int* __restrict__ list, int cap,
    float* __restrict__ out)
{
    const int e = blockIdx.x * blockDim.x + threadIdx.x;
    if (e >= NE) return;
    const int is64 = (ei[1]==0)&(ei[3]==0)&(ei[5]==0)&(ei[7]==0);
    int si, ti;
    if (is64) { si = ei[2*(size_t)e]; ti = ei[2*((size_t)NE + e)]; }
    else      { si = ei[e];           ti = ei[NE + e]; }
    const float* srcp = nf + (size_t)si * D_NODE;
    const float* tgtp = nf + (size_t)ti * D_NODE;
    const float* efp  = ef + (size_t)e  * D_EDGE;

    float acc[HID];
    #pragma unroll
    for (int j = 0; j < HID; ++j) acc[j] = b1[j];
    #pragma unroll 1
    for (int kc = 0; kc < D_IN / 16; ++kc) {
        const float* base = (kc < 4) ? (srcp + kc * 16)
                          : (kc < 8) ? (tgtp + (kc - 4) * 16)
                                     : (efp  + (kc - 8) * 16);
        float c[16];
        #pragma unroll
        for (int q = 0; q < 4; ++q) {
            const float4 v = *reinterpret_cast<const float4*>(base + q * 4);
            c[q*4+0]=v.x; c[q*4+1]=v.y; c[q*4+2]=v.z; c[q*4+3]=v.w;
        }
        #pragma unroll
        for (int j = 0; j < HID; ++j)
            #pragma unroll
            for (int q = 0; q < 16; ++q)
                acc[j] = fmaf(c[q], W1[j*D_IN + kc*16 + q], acc[j]);
    }
    #pragma unroll
    for (int j = 0; j < HID; ++j) acc[j] = fmaxf(acc[j], 0.0f);

    float logit = b3[0];
    #pragma unroll 1
    for (int jj = 0; jj < H2C; ++jj) {
        float h = b2[jj];
        #pragma unroll
        for (int j = 0; j < HID; ++j) h = fmaf(acc[j], W2[jj*HID + j], h);
        logit = fmaf(fmaxf(h, 0.0f), W3[jj], logit);
    }
    const float score = 1.0f / (1.0f + expf(-logit));
    out[e] = score;
    out[(size_t)NE + e] = (score >= 0.5f) ? 1.0f : 0.0f;
    if (fabsf(logit) < EPS2) {
        const int idx = atomicAdd(counter, 1);
        if (idx < cap) list[idx] = e;
    }
}

extern "C" void kernel_launch(void* const* d_in, const int* in_sizes, int n_in,
                              void* d_out, int out_size, void* d_ws, size_t ws_size,
                              hipStream_t stream) {
    const float* nf = (const float*)d_in[0];
    const int*   ei = (const int*)  d_in[1];
    const float* ef = (const float*)d_in[2];
    const float* W1 = (const float*)d_in[3];
    const float* b1 = (const float*)d_in[4];
    const float* W2 = (const float*)d_in[5];
    const float* b2 = (const float*)d_in[6];
    const float* W3 = (const float*)d_in[7];
    const float* b3 = (const float*)d_in[8];
    float* out = (float*)d_out;
    unsigned char* ws = (unsigned char*)d_ws;
    int* counter2 = (int*)ws;

    if (ws_size >= (size_t)WS_V8_MIN) {
        unsigned short* Uhi = (unsigned short*)(ws + WS_UHI);
        unsigned short* Ulo = (unsigned short*)(ws + WS_ULO);
        unsigned short* Vhi = (unsigned short*)(ws + WS_VHI);
        unsigned short* Vlo = (unsigned short*)(ws + WS_VLO);
        unsigned short* masks = (unsigned short*)(ws + WS_MASK);
        int* list2 = (int*)(ws + WS_L2OA);
        hipLaunchKernelGGL(prep_uv_v9, dim3(N_NODES / 32), dim3(256), 0, stream,
                           nf, W1, b1, Uhi, Ulo, Vhi, Vlo);
        hipLaunchKernelGGL(prep_pack_v8, dim3(2), dim3(256), 0, stream, W1, W2, ws);
        hipLaunchKernelGGL(edge_mlp_v8_kernel, dim3((NE + 127) / 128), dim3(256), 0, stream,
                           ei, ef, b2, W3, b3,
                           (const unsigned short*)(ws + WS_A1_OFF),
                           (const unsigned short*)(ws + WS_A2_OFF),
                           Uhi, Vhi, masks, out);
        hipLaunchKernelGGL(fixup1_v8, dim3(2048), dim3(256), 0, stream,
                           ei, ef, W1, W2, b2, W3, b3,
                           Uhi, Ulo, Vhi, Vlo, masks,
                           counter2, list2, L2_CAP, out);
        hipLaunchKernelGGL(fixup_wave_f64_kernel, dim3(256), dim3(256), 0, stream,
                           nf, ei, ef, W1, b1, W2, b2, W3, b3,
                           counter2, list2, L2_CAP, out);
    } else {
        long long cap_ll = ((long long)ws_size - 16) / 4;
        const int cap = (int)(cap_ll < 0 ? 0 : (cap_ll > NE ? NE : cap_ll));
        int* slist = (int*)(ws + 16);
        hipLaunchKernelGGL(zero_counter_kernel, dim3(1), dim3(64), 0, stream, counter2);
        hipLaunchKernelGGL(edge_mlp_f32_kernel, dim3((NE + 255)/256), dim3(256), 0, stream,
                           nf, ei, ef, W1, b1, W2, b2, W3, b3, counter2, slist, cap, out);
        hipLaunchKernelGGL(fixup_wave_f64_kernel, dim3(256), dim3(256), 0, stream,
                           nf, ei, ef, W1, b1, W2, b2, W3, b3, counter2, slist, cap, out);
    }
}

// Round 10
// 398.143 us; speedup vs baseline: 7.3523x; 1.0455x over previous
//
#include <hip/hip_runtime.h>
#include <math.h>

#define N_NODES 100000
#define NE 1000000
#define D_NODE 64
#define D_EDGE 32
#define HID 64
#define H2C 32
#define D_IN 160
#define NTILES (NE / 16)        // 62500
#define EPS1 1.5e-3f            // fp16-table bound: R6 bf16 pass at 0.012 x (2^-11/2^-8)
#define EPS2 1e-3f              // f32-path error bound (validated rounds 3-9)

typedef __attribute__((ext_vector_type(8))) short short8;   // 8 bf16 or fp16
typedef __attribute__((ext_vector_type(4))) float f32x4;

// ws byte layout (identical to rounds 8/9):
#define WS_A1_OFF 16
#define WS_A2_OFF 8208
#define WS_UHI 16640
#define TBL_BYTES (N_NODES * HID * 2)          // 12,800,000
#define WS_ULO (WS_UHI + TBL_BYTES)
#define WS_VHI (WS_ULO + TBL_BYTES)
#define WS_VLO (WS_VHI + TBL_BYTES)
#define WS_MASK (WS_VLO + TBL_BYTES)           // 51,216,640
#define WS_L2O  (WS_MASK + NTILES * 2 + 48)
#define WS_L2OA ((WS_L2O + 7) & ~7)
#define L2_CAP 65536
#define WS_V8_MIN (WS_L2OA + L2_CAP * 4)       // ~51.6 MB

__device__ __forceinline__ unsigned short bf16_rne(float x) {
    unsigned int u = __float_as_uint(x);
    u += 0x7fffu + ((u >> 16) & 1u);
    return (unsigned short)(u >> 16);
}
__device__ __forceinline__ float bf16_tof(unsigned short h) {
    return __uint_as_float(((unsigned int)h) << 16);
}
__device__ __forceinline__ float h2f(unsigned short h) {
    _Float16 x = *reinterpret_cast<const _Float16*>(&h);
    return (float)x;
}
__device__ __forceinline__ unsigned short f2h(float f) {
    _Float16 x = (_Float16)f;   // RNE
    return *reinterpret_cast<const unsigned short*>(&x);
}
__device__ __forceinline__ void split8(const float* xs, short8& hi, short8& lo) {
    #pragma unroll
    for (int i = 0; i < 8; ++i) {
        unsigned short h = bf16_rne(xs[i]);
        float fh = bf16_tof(h);
        unsigned short l = bf16_rne(xs[i] - fh);
        hi[i] = (short)h;
        lo[i] = (short)l;
    }
}

// ---- Prep 1 (v9, unchanged): LDS-broadcast node rows; 8 indep FMA accumulators ----
__global__ __launch_bounds__(256) void prep_uv_v9(
    const float* __restrict__ nf, const float* __restrict__ W1,
    const float* __restrict__ b1,
    unsigned short* __restrict__ Uhi, unsigned short* __restrict__ Ulo,
    unsigned short* __restrict__ Vhi, unsigned short* __restrict__ Vlo)
{
    __shared__ __attribute__((aligned(16))) float xs[32 * 64];  // 8 KB
    const int wave = threadIdx.x >> 6, lane = threadIdx.x & 63;

    float w[128];
    #pragma unroll
    for (int q = 0; q < 32; ++q) {
        const float4 t = *(const float4*)(W1 + lane * D_IN + q * 4);
        w[q*4+0]=t.x; w[q*4+1]=t.y; w[q*4+2]=t.z; w[q*4+3]=t.w;
    }
    const float bj = b1[lane];

    const int node0 = blockIdx.x * 32;
    {
        const float4* src = (const float4*)(nf + (size_t)node0 * 64);
        float4* dst = (float4*)xs;
        dst[threadIdx.x]       = src[threadIdx.x];
        dst[threadIdx.x + 256] = src[threadIdx.x + 256];
    }
    __syncthreads();

    #pragma unroll 1
    for (int ni = 0; ni < 8; ++ni) {
        const int nl = wave * 8 + ni;
        const int node = node0 + nl;
        const float4* xr = (const float4*)(xs + nl * 64);
        float u0 = bj, u1 = 0.f, u2 = 0.f, u3 = 0.f;
        float v0 = 0.f, v1 = 0.f, v2 = 0.f, v3 = 0.f;
        #pragma unroll
        for (int k4 = 0; k4 < 16; ++k4) {
            const float4 x = xr[k4];
            u0 = fmaf(x.x, w[k4*4+0], u0);
            u1 = fmaf(x.y, w[k4*4+1], u1);
            u2 = fmaf(x.z, w[k4*4+2], u2);
            u3 = fmaf(x.w, w[k4*4+3], u3);
            v0 = fmaf(x.x, w[64+k4*4+0], v0);
            v1 = fmaf(x.y, w[64+k4*4+1], v1);
            v2 = fmaf(x.z, w[64+k4*4+2], v2);
            v3 = fmaf(x.w, w[64+k4*4+3], v3);
        }
        const float u = (u0 + u1) + (u2 + u3);
        const float v = (v0 + v1) + (v2 + v3);
        const unsigned short uhv = f2h(u), vhv = f2h(v);
        Uhi[(size_t)node*64 + lane] = uhv;
        Ulo[(size_t)node*64 + lane] = f2h(u - h2f(uhv));
        Vhi[(size_t)node*64 + lane] = vhv;
        Vlo[(size_t)node*64 + lane] = f2h(v - h2f(vhv));
    }
}

// ---- Prep 2 (unchanged): pack W1e / W2 MFMA fragments, zero counter2 ----
__global__ void prep_pack_v8(const float* __restrict__ W1, const float* __restrict__ W2,
                             unsigned char* __restrict__ ws)
{
    const int t = blockIdx.x * blockDim.x + threadIdx.x;
    if (t == 0) { *(int*)ws = 0; }
    unsigned short* a1 = (unsigned short*)(ws + WS_A1_OFF);
    unsigned short* a2 = (unsigned short*)(ws + WS_A2_OFF);
    for (int task = t; task < 512; task += gridDim.x * blockDim.x) {
        const int isA2 = task >= 256;
        const int tt = task & 255;
        const int f = tt >> 6, l = tt & 63;
        const int l15 = l & 15, kg = l >> 4;
        const float* src;
        unsigned short* dst;
        if (!isA2) {
            src = W1 + (size_t)(f*16 + l15)*D_IN + 128 + kg*8;
            dst = a1 + ((size_t)f*64 + l)*16;
        } else {
            const int nn2 = f >> 1, kk = f & 1;
            src = W2 + (size_t)(nn2*16 + l15)*HID + kk*32 + kg*8;
            dst = a2 + ((size_t)f*64 + l)*16;
        }
        #pragma unroll
        for (int i = 0; i < 8; ++i) {
            const float wv = src[i];
            const unsigned short h = bf16_rne(wv);
            dst[i] = h;
            dst[8+i] = bf16_rne(wv - bf16_tof(h));
        }
    }
}

// ---- Main v8 (unchanged from passing rounds 8/9): fp16 tables; NO ATOMICS ----
__global__ __launch_bounds__(256) void edge_mlp_v8_kernel(
    const int* __restrict__ ei, const float* __restrict__ ef,
    const float* __restrict__ b2, const float* __restrict__ W3, const float* __restrict__ b3,
    const unsigned short* __restrict__ a1p, const unsigned short* __restrict__ a2p,
    const unsigned short* __restrict__ Uhi, const unsigned short* __restrict__ Vhi,
    unsigned short* __restrict__ maskbuf,
    float* __restrict__ out)
{
    __shared__ __attribute__((aligned(16))) float Hs[4][16][68];
    const int wave = threadIdx.x >> 6, lane = threadIdx.x & 63;
    const int l15 = lane & 15, kg = lane >> 4;
    const long long e0 = (long long)blockIdx.x * 128 + wave * 32;

    const int is64 = (ei[1]==0)&(ei[3]==0)&(ei[5]==0)&(ei[7]==0);

    int si[2], ti[2];
    const float* efpp[2];
    #pragma unroll
    for (int t = 0; t < 2; ++t) {
        long long e = e0 + t * 16 + l15;
        if (e >= NE) e = NE - 1;
        if (is64) { si[t] = ei[(size_t)(2*e)]; ti[t] = ei[(size_t)(2*(NE+e))]; }
        else      { si[t] = ei[(size_t)e];     ti[t] = ei[(size_t)(NE+e)]; }
        efpp[t] = ef + (size_t)e * D_EDGE;
    }
    float4 efv[2][2];
    #pragma unroll
    for (int t = 0; t < 2; ++t) {
        efv[t][0] = *(const float4*)(efpp[t] + kg*8);
        efv[t][1] = *(const float4*)(efpp[t] + kg*8 + 4);
    }
    short8 uh[2][2], vh[2][2];
    #pragma unroll
    for (int t = 0; t < 2; ++t)
        #pragma unroll
        for (int kk = 0; kk < 2; ++kk) {
            uh[t][kk] = *(const short8*)(Uhi + (size_t)si[t]*64 + kk*32 + kg*8);
            vh[t][kk] = *(const short8*)(Vhi + (size_t)ti[t]*64 + kk*32 + kg*8);
        }

    const f32x4 z4 = {0.f,0.f,0.f,0.f};
    f32x4 acc1[2][4];
    #pragma unroll
    for (int t = 0; t < 2; ++t) {
        float xsl[8] = {efv[t][0].x,efv[t][0].y,efv[t][0].z,efv[t][0].w,
                        efv[t][1].x,efv[t][1].y,efv[t][1].z,efv[t][1].w};
        short8 ahi, alo;
        split8(xsl, ahi, alo);
        #pragma unroll
        for (int nn = 0; nn < 4; ++nn) {
            const unsigned short* fp = a1p + ((size_t)nn*64 + lane)*16;
            const short8 bhi = *(const short8*)fp;
            const short8 blo = *(const short8*)(fp + 8);
            f32x4 a = z4;
            a = __builtin_amdgcn_mfma_f32_16x16x32_bf16(ahi, bhi, a, 0,0,0);
            a = __builtin_amdgcn_mfma_f32_16x16x32_bf16(ahi, blo, a, 0,0,0);
            a = __builtin_amdgcn_mfma_f32_16x16x32_bf16(alo, bhi, a, 0,0,0);
            acc1[t][nn] = a;
        }
    }

    const float b2a = b2[l15], b2b = b2[16 + l15];
    const float w3a = W3[l15], w3b = W3[16 + l15];
    const float b3s = b3[0];

    #pragma unroll
    for (int t = 0; t < 2; ++t) {
        #pragma unroll
        for (int nn = 0; nn < 4; ++nn)
            #pragma unroll
            for (int r = 0; r < 4; ++r)
                Hs[wave][kg*4 + r][nn*16 + l15] = acc1[t][nn][r];
        asm volatile("s_waitcnt lgkmcnt(0)" ::: "memory");

        f32x4 acc2[2] = {z4, z4};
        #pragma unroll
        for (int kk = 0; kk < 2; ++kk) {
            const float* hp = &Hs[wave][l15][kk*32 + kg*8];
            float xsl[8];
            #pragma unroll
            for (int i = 0; i < 8; ++i)
                xsl[i] = fmaxf(hp[i] + h2f((unsigned short)uh[t][kk][i])
                                     + h2f((unsigned short)vh[t][kk][i]), 0.f);
            short8 a2hi, a2lo;
            split8(xsl, a2hi, a2lo);
            #pragma unroll
            for (int nn = 0; nn < 2; ++nn) {
                const unsigned short* fp = a2p + ((size_t)(nn*2+kk)*64 + lane)*16;
                const short8 bhi = *(const short8*)fp;
                const short8 blo = *(const short8*)(fp + 8);
                acc2[nn] = __builtin_amdgcn_mfma_f32_16x16x32_bf16(a2hi, bhi, acc2[nn],0,0,0);
                acc2[nn] = __builtin_amdgcn_mfma_f32_16x16x32_bf16(a2hi, blo, acc2[nn],0,0,0);
                acc2[nn] = __builtin_amdgcn_mfma_f32_16x16x32_bf16(a2lo, bhi, acc2[nn],0,0,0);
            }
        }
        asm volatile("s_waitcnt lgkmcnt(0)" ::: "memory");

        float vv[4];
        #pragma unroll
        for (int r = 0; r < 4; ++r) {
            float x = fmaxf(acc2[0][r] + b2a, 0.f) * w3a + fmaxf(acc2[1][r] + b2b, 0.f) * w3b;
            #pragma unroll
            for (int off = 1; off < 16; off <<= 1) x += __shfl_xor(x, off, 16);
            vv[r] = x + b3s;
        }
        float lg = 0.f;
        bool valid = false;
        long long e = 0;
        if (l15 < 4) {
            lg = (l15 == 0) ? vv[0] : (l15 == 1) ? vv[1] : (l15 == 2) ? vv[2] : vv[3];
            e = e0 + t * 16 + kg * 4 + l15;
            valid = (e < NE);
            if (valid) {
                const float sc = 1.0f / (1.0f + expf(-lg));
                out[e] = sc;
                out[NE + e] = (sc >= 0.5f) ? 1.0f : 0.0f;
            }
        }
        const bool flag = valid && (fabsf(lg) < EPS1);
        const unsigned long long m = __ballot(flag);
        const unsigned int mask16 = (unsigned int)( (m & 0xFull)
                                                  | ((m >> 12) & 0xF0ull)
                                                  | ((m >> 24) & 0xF00ull)
                                                  | ((m >> 36) & 0xF000ull) );
        const long long tile = (e0 + t * 16) >> 4;
        if (lane == 0 && tile < NTILES) maskbuf[tile] = (unsigned short)mask16;
    }
}

// ---- Fixup 1: mask-driven wave-per-tile f32 recompute; ef staged via LDS ----
__global__ __launch_bounds__(256) void fixup1_v8(
    const int* __restrict__ ei, const float* __restrict__ ef,
    const float* __restrict__ W1, const float* __restrict__ W2,
    const float* __restrict__ b2, const float* __restrict__ W3, const float* __restrict__ b3,
    const unsigned short* __restrict__ Uhi, const unsigned short* __restrict__ Ulo,
    const unsigned short* __restrict__ Vhi, const unsigned short* __restrict__ Vlo,
    const unsigned short* __restrict__ maskbuf,
    int* __restrict__ counter2, int* __restrict__ list2, int cap2,
    float* __restrict__ out)
{
    __shared__ float W1e[64][33];
    __shared__ float W2s[32][65];
    __shared__ float fh[4][HID];
    __shared__ __attribute__((aligned(16))) float efs[4][32];
    const int wave = threadIdx.x >> 6, lane = threadIdx.x & 63;
    for (int i = threadIdx.x; i < 64*32; i += blockDim.x)
        W1e[i >> 5][i & 31] = W1[(size_t)(i >> 5)*D_IN + 128 + (i & 31)];
    for (int i = threadIdx.x; i < 32*64; i += blockDim.x)
        W2s[i >> 6][i & 63] = W2[i];
    __syncthreads();

    const float b2l = (lane < H2C) ? b2[lane] : 0.f;
    const float w3l = (lane < H2C) ? W3[lane] : 0.f;
    const float b3s = b3[0];
    const int nwaves = (gridDim.x * blockDim.x) >> 6;
    const int wid = (blockIdx.x * blockDim.x + threadIdx.x) >> 6;
    const int is64 = (ei[1]==0)&(ei[3]==0)&(ei[5]==0)&(ei[7]==0);

    for (int tile = wid; tile < NTILES; tile += nwaves) {
        unsigned int mask = maskbuf[tile];
        while (mask) {
            const int b = __ffs(mask) - 1;
            mask &= mask - 1;
            const int e = tile * 16 + b;
            int si, ti;
            if (is64) { si = ei[(size_t)2*e]; ti = ei[(size_t)2*(NE + (long long)e)]; }
            else      { si = ei[e];           ti = ei[NE + (size_t)e]; }
            const float u = h2f(Uhi[(size_t)si*64 + lane]) + h2f(Ulo[(size_t)si*64 + lane]);
            const float v = h2f(Vhi[(size_t)ti*64 + lane]) + h2f(Vlo[(size_t)ti*64 + lane]);
            // Stage ef row: one coalesced 128B load by lanes 0-7.
            if (lane < 8)
                ((float4*)efs[wave])[lane] =
                    ((const float4*)(ef + (size_t)e * D_EDGE))[lane];
            asm volatile("s_waitcnt lgkmcnt(0)" ::: "memory");
            float p0 = u + v, p1 = 0.f, p2 = 0.f, p3 = 0.f;
            #pragma unroll
            for (int k = 0; k < 32; k += 4) {
                p0 = fmaf(efs[wave][k+0], W1e[lane][k+0], p0);
                p1 = fmaf(efs[wave][k+1], W1e[lane][k+1], p1);
                p2 = fmaf(efs[wave][k+2], W1e[lane][k+2], p2);
                p3 = fmaf(efs[wave][k+3], W1e[lane][k+3], p3);
            }
            fh[wave][lane] = fmaxf((p0 + p1) + (p2 + p3), 0.f);
            asm volatile("s_waitcnt lgkmcnt(0)" ::: "memory");

            float tsum = 0.f;
            if (lane < H2C) {
                float h0 = b2l, h1 = 0.f, h2 = 0.f, h3 = 0.f;
                #pragma unroll
                for (int j = 0; j < 64; j += 4) {
                    h0 = fmaf(fh[wave][j+0], W2s[lane][j+0], h0);
                    h1 = fmaf(fh[wave][j+1], W2s[lane][j+1], h1);
                    h2 = fmaf(fh[wave][j+2], W2s[lane][j+2], h2);
                    h3 = fmaf(fh[wave][j+3], W2s[lane][j+3], h3);
                }
                tsum = fmaxf((h0 + h1) + (h2 + h3), 0.f) * w3l;
            }
            #pragma unroll
            for (int off = 1; off < 32; off <<= 1) tsum += __shfl_xor(tsum, off, 32);
            if (lane == 0) {
                const float lg = tsum + b3s;
                const float sc = 1.0f / (1.0f + expf(-lg));
                out[e] = sc;
                out[NE + (size_t)e] = (sc >= 0.5f) ? 1.0f : 0.0f;
                if (fabsf(lg) < EPS2) {
                    const int idx = atomicAdd(counter2, 1);
                    if (idx < cap2) list2[idx] = e;
                }
            }
            asm volatile("s_waitcnt lgkmcnt(0)" ::: "memory");
        }
    }
}

// ---- Fixup 2: f64 exact over list2; rows staged via coalesced LDS ----
__global__ __launch_bounds__(256) void fixup_wave_f64_kernel(
    const float* __restrict__ nf, const int* __restrict__ ei,
    const float* __restrict__ ef,
    const float* __restrict__ W1, const float* __restrict__ b1,
    const float* __restrict__ W2, const float* __restrict__ b2,
    const float* __restrict__ W3, const float* __restrict__ b3,
    const int* __restrict__ counter, const int* __restrict__ list, int cap,
    float* __restrict__ out)
{
    __shared__ double fh[4][HID];
    __shared__ __attribute__((aligned(16))) float rows[4][160];  // sp|tp|ep
    const int wave = threadIdx.x >> 6, lane = threadIdx.x & 63;
    const int nwaves = (gridDim.x * blockDim.x) >> 6;
    const int wid = (blockIdx.x * blockDim.x + threadIdx.x) >> 6;
    int n = counter[0]; if (n > cap) n = cap;
    const int is64 = (ei[1]==0)&(ei[3]==0)&(ei[5]==0)&(ei[7]==0);

    for (int i = wid; i < n; i += nwaves) {
        const int e = list[i];
        int si, ti;
        if (is64) { si = ei[(size_t)2*e]; ti = ei[(size_t)2*(NE + (long long)e)]; }
        else      { si = ei[e];           ti = ei[NE + (size_t)e]; }
        const float* sp = nf + (size_t)si * D_NODE;
        const float* tp = nf + (size_t)ti * D_NODE;
        const float* ep = ef + (size_t)e * D_EDGE;

        // Coalesced staging: lanes 0-15 sp, 16-31 tp, 32-39 ep (float4 each).
        if (lane < 16)      ((float4*)&rows[wave][0])[lane]        = ((const float4*)sp)[lane];
        else if (lane < 32) ((float4*)&rows[wave][64])[lane - 16]  = ((const float4*)tp)[lane - 16];
        else if (lane < 40) ((float4*)&rows[wave][128])[lane - 32] = ((const float4*)ep)[lane - 32];
        asm volatile("s_waitcnt lgkmcnt(0)" ::: "memory");

        const float* rw = rows[wave];
        double a0 = (double)b1[lane], a1 = 0.0, a2 = 0.0, a3 = 0.0;
        const float* w1r = W1 + (size_t)lane * D_IN;
        #pragma unroll 4
        for (int k = 0; k < 160; k += 4) {
            a0 = fma((double)rw[k+0], (double)w1r[k+0], a0);
            a1 = fma((double)rw[k+1], (double)w1r[k+1], a1);
            a2 = fma((double)rw[k+2], (double)w1r[k+2], a2);
            a3 = fma((double)rw[k+3], (double)w1r[k+3], a3);
        }
        fh[wave][lane] = fmax((a0 + a1) + (a2 + a3), 0.0);
        asm volatile("s_waitcnt lgkmcnt(0)" ::: "memory");

        double tsum = 0.0;
        if (lane < H2C) {
            double h0 = (double)b2[lane], h1 = 0.0, h2 = 0.0, h3 = 0.0;
            const float* w2r = W2 + (size_t)lane * HID;
            #pragma unroll 4
            for (int j = 0; j < 64; j += 4) {
                h0 = fma(fh[wave][j+0], (double)w2r[j+0], h0);
                h1 = fma(fh[wave][j+1], (double)w2r[j+1], h1);
                h2 = fma(fh[wave][j+2], (double)w2r[j+2], h2);
                h3 = fma(fh[wave][j+3], (double)w2r[j+3], h3);
            }
            tsum = fmax((h0 + h1) + (h2 + h3), 0.0) * (double)W3[lane];
        }
        #pragma unroll
        for (int off = 1; off < 32; off <<= 1) tsum += __shfl_xor(tsum, off, 32);
        if (lane == 0) {
            const double logit = tsum + (double)b3[0];
            const float sc = (float)(1.0 / (1.0 + exp(-logit)));
            out[e] = sc;
            out[NE + (size_t)e] = (sc >= 0.5f) ? 1.0f : 0.0f;
        }
        asm volatile("s_waitcnt lgkmcnt(0)" ::: "memory");
    }
}

// ---------- Fallback (tiny ws): proven f32 VALU path ----------
__global__ void zero_counter_kernel(int* __restrict__ c) {
    if (blockIdx.x == 0 && threadIdx.x == 0) c[0] = 0;
}

__global__ __launch_bounds__(256, 4) void edge_mlp_f32_kernel(
    const float* __restrict__ nf, const int* __restrict__ ei,
    const float* __restrict__ ef,
    const float* __restrict__ W1, const float* __restrict__ b1,
    const float* __restrict__ W2, const float* __restrict__ b2,
    const float* __restrict__ W3, const float* __restrict__ b3,
    int* __restrict__ counter, int* __restrict__ list, int cap,
    float* __restrict__ out)
{
    const int e = blockIdx.x * blockDim.x + threadIdx.x;
    if (e >= NE) return;
    const int is64 = (ei[1]==0)&(ei[3]==0)&(ei[5]==0)&(ei[7]==0);
    int si, ti;
    if (is64) { si = ei[2*(size_t)e]; ti = ei[2*((size_t)NE + e)]; }
    else      { si = ei[e];           ti = ei[NE + e]; }
    const float* srcp = nf + (size_t)si * D_NODE;
    const float* tgtp = nf + (size_t)ti * D_NODE;
    const float* efp  = ef + (size_t)e  * D_EDGE;

    float acc[HID];
    #pragma unroll
    for (int j = 0; j < HID; ++j) acc[j] = b1[j];
    #pragma unroll 1
    for (int kc = 0; kc < D_IN / 16; ++kc) {
        const float* base = (kc < 4) ? (srcp + kc * 16)
                          : (kc < 8) ? (tgtp + (kc - 4) * 16)
                                     : (efp  + (kc - 8) * 16);
        float c[16];
        #pragma unroll
        for (int q = 0; q < 4; ++q) {
            const float4 v = *reinterpret_cast<const float4*>(base + q * 4);
            c[q*4+0]=v.x; c[q*4+1]=v.y; c[q*4+2]=v.z; c[q*4+3]=v.w;
        }
        #pragma unroll
        for (int j = 0; j < HID; ++j)
            #pragma unroll
            for (int q = 0; q < 16; ++q)
                acc[j] = fmaf(c[q], W1[j*D_IN + kc*16 + q], acc[j]);
    }
    #pragma unroll
    for (int j = 0; j < HID; ++j) acc[j] = fmaxf(acc[j], 0.0f);

    float logit = b3[0];
    #pragma unroll 1
    for (int jj = 0; jj < H2C; ++jj) {
        float h = b2[jj];
        #pragma unroll
        for (int j = 0; j < HID; ++j) h = fmaf(acc[j], W2[jj*HID + j], h);
        logit = fmaf(fmaxf(h, 0.0f), W3[jj], logit);
    }
    const float score = 1.0f / (1.0f + expf(-logit));
    out[e] = score;
    out[(size_t)NE + e] = (score >= 0.5f) ? 1.0f : 0.0f;
    if (fabsf(logit) < EPS2) {
        const int idx = atomicAdd(counter, 1);
        if (idx < cap) list[idx] = e;
    }
}

extern "C" void kernel_launch(void* const* d_in, const int* in_sizes, int n_in,
                              void* d_out, int out_size, void* d_ws, size_t ws_size,
                              hipStream_t stream) {
    const float* nf = (const float*)d_in[0];
    const int*   ei = (const int*)  d_in[1];
    const float* ef = (const float*)d_in[2];
    const float* W1 = (const float*)d_in[3];
    const float* b1 = (const float*)d_in[4];
    const float* W2 = (const float*)d_in[5];
    const float* b2 = (const float*)d_in[6];
    const float* W3 = (const float*)d_in[7];
    const float* b3 = (const float*)d_in[8];
    float* out = (float*)d_out;
    unsigned char* ws = (unsigned char*)d_ws;
    int* counter2 = (int*)ws;

    if (ws_size >= (size_t)WS_V8_MIN) {
        unsigned short* Uhi = (unsigned short*)(ws + WS_UHI);
        unsigned short* Ulo = (unsigned short*)(ws + WS_ULO);
        unsigned short* Vhi = (unsigned short*)(ws + WS_VHI);
        unsigned short* Vlo = (unsigned short*)(ws + WS_VLO);
        unsigned short* masks = (unsigned short*)(ws + WS_MASK);
        int* list2 = (int*)(ws + WS_L2OA);
        hipLaunchKernelGGL(prep_uv_v9, dim3(N_NODES / 32), dim3(256), 0, stream,
                           nf, W1, b1, Uhi, Ulo, Vhi, Vlo);
        hipLaunchKernelGGL(prep_pack_v8, dim3(2), dim3(256), 0, stream, W1, W2, ws);
        hipLaunchKernelGGL(edge_mlp_v8_kernel, dim3((NE + 127) / 128), dim3(256), 0, stream,
                           ei, ef, b2, W3, b3,
                           (const unsigned short*)(ws + WS_A1_OFF),
                           (const unsigned short*)(ws + WS_A2_OFF),
                           Uhi, Vhi, masks, out);
        hipLaunchKernelGGL(fixup1_v8, dim3(2048), dim3(256), 0, stream,
                           ei, ef, W1, W2, b2, W3, b3,
                           Uhi, Ulo, Vhi, Vlo, masks,
                           counter2, list2, L2_CAP, out);
        hipLaunchKernelGGL(fixup_wave_f64_kernel, dim3(512), dim3(256), 0, stream,
                           nf, ei, ef, W1, b1, W2, b2, W3, b3,
                           counter2, list2, L2_CAP, out);
    } else {
        long long cap_ll = ((long long)ws_size - 16) / 4;
        const int cap = (int)(cap_ll < 0 ? 0 : (cap_ll > NE ? NE : cap_ll));
        int* slist = (int*)(ws + 16);
        hipLaunchKernelGGL(zero_counter_kernel, dim3(1), dim3(64), 0, stream, counter2);
        hipLaunchKernelGGL(edge_mlp_f32_kernel, dim3((NE + 255)/256), dim3(256), 0, stream,
                           nf, ei, ef, W1, b1, W2, b2, W3, b3, counter2, slist, cap, out);
        hipLaunchKernelGGL(fixup_wave_f64_kernel, dim3(512), dim3(256), 0, stream,
                           nf, ei, ef, W1, b1, W2, b2, W3, b3, counter2, slist, cap, out);
    }
}

// Round 11
// 302.901 us; speedup vs baseline: 9.6641x; 1.3144x over previous
//
#include <hip/hip_runtime.h>
#include <math.h>

#define N_NODES 100000
#define NE 1000000
#define D_NODE 64
#define D_EDGE 32
#define HID 64
#define H2C 32
#define D_IN 160
#define NTILES (NE / 16)        // 62500
#define CHUNK 8                 // tiles per wave in fixup scans
#define EPS1 1.5e-3f            // fp16-table bound (validated round 10)
#define EPS2 1e-3f              // f32-path bound (validated rounds 3-10)

typedef __attribute__((ext_vector_type(8))) short short8;   // 8 bf16 or fp16
typedef __attribute__((ext_vector_type(4))) float f32x4;

// ws byte layout (v11):
#define WS_A1_OFF 16
#define WS_A2_OFF 8208
#define WS_UHI 16640
#define TBL_BYTES (N_NODES * HID * 2)          // 12,800,000
#define WS_ULO (WS_UHI + TBL_BYTES)
#define WS_VHI (WS_ULO + TBL_BYTES)
#define WS_VLO (WS_VHI + TBL_BYTES)
#define WS_MASK (WS_VLO + TBL_BYTES)           // 51,216,640 (16B aligned)
#define WS_MASK2 (WS_MASK + 125008)            // 51,341,648 (16B aligned)
#define WS_V11_MIN (WS_MASK2 + 125008 + 131072) // pad for uint4 tail over-write

__device__ __forceinline__ unsigned short bf16_rne(float x) {
    unsigned int u = __float_as_uint(x);
    u += 0x7fffu + ((u >> 16) & 1u);
    return (unsigned short)(u >> 16);
}
__device__ __forceinline__ float bf16_tof(unsigned short h) {
    return __uint_as_float(((unsigned int)h) << 16);
}
__device__ __forceinline__ float h2f(unsigned short h) {
    _Float16 x = *reinterpret_cast<const _Float16*>(&h);
    return (float)x;
}
__device__ __forceinline__ unsigned short f2h(float f) {
    _Float16 x = (_Float16)f;   // RNE
    return *reinterpret_cast<const unsigned short*>(&x);
}
__device__ __forceinline__ void split8(const float* xs, short8& hi, short8& lo) {
    #pragma unroll
    for (int i = 0; i < 8; ++i) {
        unsigned short h = bf16_rne(xs[i]);
        float fh = bf16_tof(h);
        unsigned short l = bf16_rne(xs[i] - fh);
        hi[i] = (short)h;
        lo[i] = (short)l;
    }
}

// ---- Prep 1 (unchanged, passing): LDS-broadcast node rows ----
__global__ __launch_bounds__(256) void prep_uv_v9(
    const float* __restrict__ nf, const float* __restrict__ W1,
    const float* __restrict__ b1,
    unsigned short* __restrict__ Uhi, unsigned short* __restrict__ Ulo,
    unsigned short* __restrict__ Vhi, unsigned short* __restrict__ Vlo)
{
    __shared__ __attribute__((aligned(16))) float xs[32 * 64];
    const int wave = threadIdx.x >> 6, lane = threadIdx.x & 63;

    float w[128];
    #pragma unroll
    for (int q = 0; q < 32; ++q) {
        const float4 t = *(const float4*)(W1 + lane * D_IN + q * 4);
        w[q*4+0]=t.x; w[q*4+1]=t.y; w[q*4+2]=t.z; w[q*4+3]=t.w;
    }
    const float bj = b1[lane];

    const int node0 = blockIdx.x * 32;
    {
        const float4* src = (const float4*)(nf + (size_t)node0 * 64);
        float4* dst = (float4*)xs;
        dst[threadIdx.x]       = src[threadIdx.x];
        dst[threadIdx.x + 256] = src[threadIdx.x + 256];
    }
    __syncthreads();

    #pragma unroll 1
    for (int ni = 0; ni < 8; ++ni) {
        const int nl = wave * 8 + ni;
        const int node = node0 + nl;
        const float4* xr = (const float4*)(xs + nl * 64);
        float u0 = bj, u1 = 0.f, u2 = 0.f, u3 = 0.f;
        float v0 = 0.f, v1 = 0.f, v2 = 0.f, v3 = 0.f;
        #pragma unroll
        for (int k4 = 0; k4 < 16; ++k4) {
            const float4 x = xr[k4];
            u0 = fmaf(x.x, w[k4*4+0], u0);
            u1 = fmaf(x.y, w[k4*4+1], u1);
            u2 = fmaf(x.z, w[k4*4+2], u2);
            u3 = fmaf(x.w, w[k4*4+3], u3);
            v0 = fmaf(x.x, w[64+k4*4+0], v0);
            v1 = fmaf(x.y, w[64+k4*4+1], v1);
            v2 = fmaf(x.z, w[64+k4*4+2], v2);
            v3 = fmaf(x.w, w[64+k4*4+3], v3);
        }
        const float u = (u0 + u1) + (u2 + u3);
        const float v = (v0 + v1) + (v2 + v3);
        const unsigned short uhv = f2h(u), vhv = f2h(v);
        Uhi[(size_t)node*64 + lane] = uhv;
        Ulo[(size_t)node*64 + lane] = f2h(u - h2f(uhv));
        Vhi[(size_t)node*64 + lane] = vhv;
        Vlo[(size_t)node*64 + lane] = f2h(v - h2f(vhv));
    }
}

// ---- Prep 2 (unchanged): pack W1e / W2 MFMA fragments ----
__global__ void prep_pack_v8(const float* __restrict__ W1, const float* __restrict__ W2,
                             unsigned char* __restrict__ ws)
{
    const int t = blockIdx.x * blockDim.x + threadIdx.x;
    if (t == 0) { *(int*)ws = 0; }
    unsigned short* a1 = (unsigned short*)(ws + WS_A1_OFF);
    unsigned short* a2 = (unsigned short*)(ws + WS_A2_OFF);
    for (int task = t; task < 512; task += gridDim.x * blockDim.x) {
        const int isA2 = task >= 256;
        const int tt = task & 255;
        const int f = tt >> 6, l = tt & 63;
        const int l15 = l & 15, kg = l >> 4;
        const float* src;
        unsigned short* dst;
        if (!isA2) {
            src = W1 + (size_t)(f*16 + l15)*D_IN + 128 + kg*8;
            dst = a1 + ((size_t)f*64 + l)*16;
        } else {
            const int nn2 = f >> 1, kk = f & 1;
            src = W2 + (size_t)(nn2*16 + l15)*HID + kk*32 + kg*8;
            dst = a2 + ((size_t)f*64 + l)*16;
        }
        #pragma unroll
        for (int i = 0; i < 8; ++i) {
            const float wv = src[i];
            const unsigned short h = bf16_rne(wv);
            dst[i] = h;
            dst[8+i] = bf16_rne(wv - bf16_tof(h));
        }
    }
}

// ---- Main v8 (unchanged from passing rounds 8-10) ----
__global__ __launch_bounds__(256) void edge_mlp_v8_kernel(
    const int* __restrict__ ei, const float* __restrict__ ef,
    const float* __restrict__ b2, const float* __restrict__ W3, const float* __restrict__ b3,
    const unsigned short* __restrict__ a1p, const unsigned short* __restrict__ a2p,
    const unsigned short* __restrict__ Uhi, const unsigned short* __restrict__ Vhi,
    unsigned short* __restrict__ maskbuf,
    float* __restrict__ out)
{
    __shared__ __attribute__((aligned(16))) float Hs[4][16][68];
    const int wave = threadIdx.x >> 6, lane = threadIdx.x & 63;
    const int l15 = lane & 15, kg = lane >> 4;
    const long long e0 = (long long)blockIdx.x * 128 + wave * 32;

    const int is64 = (ei[1]==0)&(ei[3]==0)&(ei[5]==0)&(ei[7]==0);

    int si[2], ti[2];
    const float* efpp[2];
    #pragma unroll
    for (int t = 0; t < 2; ++t) {
        long long e = e0 + t * 16 + l15;
        if (e >= NE) e = NE - 1;
        if (is64) { si[t] = ei[(size_t)(2*e)]; ti[t] = ei[(size_t)(2*(NE+e))]; }
        else      { si[t] = ei[(size_t)e];     ti[t] = ei[(size_t)(NE+e)]; }
        efpp[t] = ef + (size_t)e * D_EDGE;
    }
    float4 efv[2][2];
    #pragma unroll
    for (int t = 0; t < 2; ++t) {
        efv[t][0] = *(const float4*)(efpp[t] + kg*8);
        efv[t][1] = *(const float4*)(efpp[t] + kg*8 + 4);
    }
    short8 uh[2][2], vh[2][2];
    #pragma unroll
    for (int t = 0; t < 2; ++t)
        #pragma unroll
        for (int kk = 0; kk < 2; ++kk) {
            uh[t][kk] = *(const short8*)(Uhi + (size_t)si[t]*64 + kk*32 + kg*8);
            vh[t][kk] = *(const short8*)(Vhi + (size_t)ti[t]*64 + kk*32 + kg*8);
        }

    const f32x4 z4 = {0.f,0.f,0.f,0.f};
    f32x4 acc1[2][4];
    #pragma unroll
    for (int t = 0; t < 2; ++t) {
        float xsl[8] = {efv[t][0].x,efv[t][0].y,efv[t][0].z,efv[t][0].w,
                        efv[t][1].x,efv[t][1].y,efv[t][1].z,efv[t][1].w};
        short8 ahi, alo;
        split8(xsl, ahi, alo);
        #pragma unroll
        for (int nn = 0; nn < 4; ++nn) {
            const unsigned short* fp = a1p + ((size_t)nn*64 + lane)*16;
            const short8 bhi = *(const short8*)fp;
            const short8 blo = *(const short8*)(fp + 8);
            f32x4 a = z4;
            a = __builtin_amdgcn_mfma_f32_16x16x32_bf16(ahi, bhi, a, 0,0,0);
            a = __builtin_amdgcn_mfma_f32_16x16x32_bf16(ahi, blo, a, 0,0,0);
            a = __builtin_amdgcn_mfma_f32_16x16x32_bf16(alo, bhi, a, 0,0,0);
            acc1[t][nn] = a;
        }
    }

    const float b2a = b2[l15], b2b = b2[16 + l15];
    const float w3a = W3[l15], w3b = W3[16 + l15];
    const float b3s = b3[0];

    #pragma unroll
    for (int t = 0; t < 2; ++t) {
        #pragma unroll
        for (int nn = 0; nn < 4; ++nn)
            #pragma unroll
            for (int r = 0; r < 4; ++r)
                Hs[wave][kg*4 + r][nn*16 + l15] = acc1[t][nn][r];
        asm volatile("s_waitcnt lgkmcnt(0)" ::: "memory");

        f32x4 acc2[2] = {z4, z4};
        #pragma unroll
        for (int kk = 0; kk < 2; ++kk) {
            const float* hp = &Hs[wave][l15][kk*32 + kg*8];
            float xsl[8];
            #pragma unroll
            for (int i = 0; i < 8; ++i)
                xsl[i] = fmaxf(hp[i] + h2f((unsigned short)uh[t][kk][i])
                                     + h2f((unsigned short)vh[t][kk][i]), 0.f);
            short8 a2hi, a2lo;
            split8(xsl, a2hi, a2lo);
            #pragma unroll
            for (int nn = 0; nn < 2; ++nn) {
                const unsigned short* fp = a2p + ((size_t)(nn*2+kk)*64 + lane)*16;
                const short8 bhi = *(const short8*)fp;
                const short8 blo = *(const short8*)(fp + 8);
                acc2[nn] = __builtin_amdgcn_mfma_f32_16x16x32_bf16(a2hi, bhi, acc2[nn],0,0,0);
                acc2[nn] = __builtin_amdgcn_mfma_f32_16x16x32_bf16(a2hi, blo, acc2[nn],0,0,0);
                acc2[nn] = __builtin_amdgcn_mfma_f32_16x16x32_bf16(a2lo, bhi, acc2[nn],0,0,0);
            }
        }
        asm volatile("s_waitcnt lgkmcnt(0)" ::: "memory");

        float vv[4];
        #pragma unroll
        for (int r = 0; r < 4; ++r) {
            float x = fmaxf(acc2[0][r] + b2a, 0.f) * w3a + fmaxf(acc2[1][r] + b2b, 0.f) * w3b;
            #pragma unroll
            for (int off = 1; off < 16; off <<= 1) x += __shfl_xor(x, off, 16);
            vv[r] = x + b3s;
        }
        float lg = 0.f;
        bool valid = false;
        long long e = 0;
        if (l15 < 4) {
            lg = (l15 == 0) ? vv[0] : (l15 == 1) ? vv[1] : (l15 == 2) ? vv[2] : vv[3];
            e = e0 + t * 16 + kg * 4 + l15;
            valid = (e < NE);
            if (valid) {
                const float sc = 1.0f / (1.0f + expf(-lg));
                out[e] = sc;
                out[NE + e] = (sc >= 0.5f) ? 1.0f : 0.0f;
            }
        }
        const bool flag = valid && (fabsf(lg) < EPS1);
        const unsigned long long m = __ballot(flag);
        const unsigned int mask16 = (unsigned int)( (m & 0xFull)
                                                  | ((m >> 12) & 0xF0ull)
                                                  | ((m >> 24) & 0xF00ull)
                                                  | ((m >> 36) & 0xF000ull) );
        const long long tile = (e0 + t * 16) >> 4;
        if (lane == 0 && tile < NTILES) maskbuf[tile] = (unsigned short)mask16;
    }
}

// ---- Fixup 1 (v11): chunked mask scan, f32 recompute, writes mask2 — NO ATOMICS ----
__global__ __launch_bounds__(256) void fixup1_v11(
    const int* __restrict__ ei, const float* __restrict__ ef,
    const float* __restrict__ W1, const float* __restrict__ W2,
    const float* __restrict__ b2, const float* __restrict__ W3, const float* __restrict__ b3,
    const unsigned short* __restrict__ Uhi, const unsigned short* __restrict__ Ulo,
    const unsigned short* __restrict__ Vhi, const unsigned short* __restrict__ Vlo,
    const unsigned short* __restrict__ mask1, unsigned short* __restrict__ mask2,
    float* __restrict__ out)
{
    __shared__ float W1e[64][33];
    __shared__ float W2s[32][65];
    __shared__ float fh[4][HID];
    __shared__ __attribute__((aligned(16))) float efs[4][32];
    const int wave = threadIdx.x >> 6, lane = threadIdx.x & 63;
    for (int i = threadIdx.x; i < 64*32; i += blockDim.x)
        W1e[i >> 5][i & 31] = W1[(size_t)(i >> 5)*D_IN + 128 + (i & 31)];
    for (int i = threadIdx.x; i < 32*64; i += blockDim.x)
        W2s[i >> 6][i & 63] = W2[i];
    __syncthreads();

    const float b2l = (lane < H2C) ? b2[lane] : 0.f;
    const float w3l = (lane < H2C) ? W3[lane] : 0.f;
    const float b3s = b3[0];
    const int wid = (blockIdx.x * blockDim.x + threadIdx.x) >> 6;
    const int base_tile = wid * CHUNK;
    if (base_tile >= NTILES) return;
    const int is64 = (ei[1]==0)&(ei[3]==0)&(ei[5]==0)&(ei[7]==0);

    // One 16B read covers this wave's 8 tiles.
    const uint4 mv = *(const uint4*)((const unsigned char*)mask1 + (size_t)wid * 16);
    const unsigned int mw[4] = {mv.x, mv.y, mv.z, mv.w};
    unsigned int m2w[4] = {0, 0, 0, 0};

    #pragma unroll 1
    for (int j = 0; j < CHUNK; ++j) {
        const int tile = base_tile + j;
        if (tile >= NTILES) break;
        unsigned int mask = (mw[j >> 1] >> ((j & 1) * 16)) & 0xFFFFu;
        unsigned int m2 = 0;
        while (mask) {
            const int b = __ffs(mask) - 1;
            mask &= mask - 1;
            const int e = tile * 16 + b;
            int si, ti;
            if (is64) { si = ei[(size_t)2*e]; ti = ei[(size_t)2*(NE + (long long)e)]; }
            else      { si = ei[e];           ti = ei[NE + (size_t)e]; }
            const float u = h2f(Uhi[(size_t)si*64 + lane]) + h2f(Ulo[(size_t)si*64 + lane]);
            const float v = h2f(Vhi[(size_t)ti*64 + lane]) + h2f(Vlo[(size_t)ti*64 + lane]);
            if (lane < 8)
                ((float4*)efs[wave])[lane] =
                    ((const float4*)(ef + (size_t)e * D_EDGE))[lane];
            asm volatile("s_waitcnt lgkmcnt(0)" ::: "memory");
            float p0 = u + v, p1 = 0.f, p2 = 0.f, p3 = 0.f;
            #pragma unroll
            for (int k = 0; k < 32; k += 4) {
                p0 = fmaf(efs[wave][k+0], W1e[lane][k+0], p0);
                p1 = fmaf(efs[wave][k+1], W1e[lane][k+1], p1);
                p2 = fmaf(efs[wave][k+2], W1e[lane][k+2], p2);
                p3 = fmaf(efs[wave][k+3], W1e[lane][k+3], p3);
            }
            fh[wave][lane] = fmaxf((p0 + p1) + (p2 + p3), 0.f);
            asm volatile("s_waitcnt lgkmcnt(0)" ::: "memory");

            float tsum = 0.f;
            if (lane < H2C) {
                float h0 = b2l, h1 = 0.f, h2 = 0.f, h3 = 0.f;
                #pragma unroll
                for (int jj = 0; jj < 64; jj += 4) {
                    h0 = fmaf(fh[wave][jj+0], W2s[lane][jj+0], h0);
                    h1 = fmaf(fh[wave][jj+1], W2s[lane][jj+1], h1);
                    h2 = fmaf(fh[wave][jj+2], W2s[lane][jj+2], h2);
                    h3 = fmaf(fh[wave][jj+3], W2s[lane][jj+3], h3);
                }
                tsum = fmaxf((h0 + h1) + (h2 + h3), 0.f) * w3l;
            }
            #pragma unroll
            for (int off = 1; off < 32; off <<= 1) tsum += __shfl_xor(tsum, off, 32);
            int refl = 0;
            if (lane == 0) {
                const float lg = tsum + b3s;
                const float sc = 1.0f / (1.0f + expf(-lg));
                out[e] = sc;
                out[NE + (size_t)e] = (sc >= 0.5f) ? 1.0f : 0.0f;
                refl = (fabsf(lg) < EPS2) ? 1 : 0;
            }
            refl = __shfl(refl, 0, 64);           // wave-uniform re-flag bit
            m2 |= ((unsigned int)refl) << b;
            asm volatile("s_waitcnt lgkmcnt(0)" ::: "memory");
        }
        m2w[j >> 1] |= m2 << ((j & 1) * 16);
    }
    if (lane == 0) {
        uint4 o; o.x = m2w[0]; o.y = m2w[1]; o.z = m2w[2]; o.w = m2w[3];
        *(uint4*)((unsigned char*)mask2 + (size_t)wid * 16) = o;
    }
}

// ---- Fixup 2 (v11): mask2-driven f64 exact — NO ATOMICS ----
__global__ __launch_bounds__(256) void fixup2_v11(
    const float* __restrict__ nf, const int* __restrict__ ei,
    const float* __restrict__ ef,
    const float* __restrict__ W1, const float* __restrict__ b1,
    const float* __restrict__ W2, const float* __restrict__ b2,
    const float* __restrict__ W3, const float* __restrict__ b3,
    const unsigned short* __restrict__ mask2,
    float* __restrict__ out)
{
    __shared__ double fh[4][HID];
    __shared__ __attribute__((aligned(16))) float rows[4][160];
    const int wave = threadIdx.x >> 6, lane = threadIdx.x & 63;
    const int wid = (blockIdx.x * blockDim.x + threadIdx.x) >> 6;
    const int base_tile = wid * CHUNK;
    if (base_tile >= NTILES) return;
    const int is64 = (ei[1]==0)&(ei[3]==0)&(ei[5]==0)&(ei[7]==0);

    const uint4 mv = *(const uint4*)((const unsigned char*)mask2 + (size_t)wid * 16);
    const unsigned int mw[4] = {mv.x, mv.y, mv.z, mv.w};

    #pragma unroll 1
    for (int j = 0; j < CHUNK; ++j) {
        const int tile = base_tile + j;
        if (tile >= NTILES) break;
        unsigned int mask = (mw[j >> 1] >> ((j & 1) * 16)) & 0xFFFFu;
        while (mask) {
            const int b = __ffs(mask) - 1;
            mask &= mask - 1;
            const int e = tile * 16 + b;
            int si, ti;
            if (is64) { si = ei[(size_t)2*e]; ti = ei[(size_t)2*(NE + (long long)e)]; }
            else      { si = ei[e];           ti = ei[NE + (size_t)e]; }
            const float* sp = nf + (size_t)si * D_NODE;
            const float* tp = nf + (size_t)ti * D_NODE;
            const float* ep = ef + (size_t)e * D_EDGE;

            if (lane < 16)      ((float4*)&rows[wave][0])[lane]        = ((const float4*)sp)[lane];
            else if (lane < 32) ((float4*)&rows[wave][64])[lane - 16]  = ((const float4*)tp)[lane - 16];
            else if (lane < 40) ((float4*)&rows[wave][128])[lane - 32] = ((const float4*)ep)[lane - 32];
            asm volatile("s_waitcnt lgkmcnt(0)" ::: "memory");

            const float* rw = rows[wave];
            double a0 = (double)b1[lane], a1 = 0.0, a2 = 0.0, a3 = 0.0;
            const float* w1r = W1 + (size_t)lane * D_IN;
            #pragma unroll 4
            for (int k = 0; k < 160; k += 4) {
                a0 = fma((double)rw[k+0], (double)w1r[k+0], a0);
                a1 = fma((double)rw[k+1], (double)w1r[k+1], a1);
                a2 = fma((double)rw[k+2], (double)w1r[k+2], a2);
                a3 = fma((double)rw[k+3], (double)w1r[k+3], a3);
            }
            fh[wave][lane] = fmax((a0 + a1) + (a2 + a3), 0.0);
            asm volatile("s_waitcnt lgkmcnt(0)" ::: "memory");

            double tsum = 0.0;
            if (lane < H2C) {
                double h0 = (double)b2[lane], h1 = 0.0, h2 = 0.0, h3 = 0.0;
                const float* w2r = W2 + (size_t)lane * HID;
                #pragma unroll 4
                for (int jj = 0; jj < 64; jj += 4) {
                    h0 = fma(fh[wave][jj+0], (double)w2r[jj+0], h0);
                    h1 = fma(fh[wave][jj+1], (double)w2r[jj+1], h1);
                    h2 = fma(fh[wave][jj+2], (double)w2r[jj+2], h2);
                    h3 = fma(fh[wave][jj+3], (double)w2r[jj+3], h3);
                }
                tsum = fmax((h0 + h1) + (h2 + h3), 0.0) * (double)W3[lane];
            }
            #pragma unroll
            for (int off = 1; off < 32; off <<= 1) tsum += __shfl_xor(tsum, off, 32);
            if (lane == 0) {
                const double logit = tsum + (double)b3[0];
                const float sc = (float)(1.0 / (1.0 + exp(-logit)));
                out[e] = sc;
                out[NE + (size_t)e] = (sc >= 0.5f) ? 1.0f : 0.0f;
            }
            asm volatile("s_waitcnt lgkmcnt(0)" ::: "memory");
        }
    }
}

// ---------- Fallback (tiny ws): proven f32 VALU path + atomic list ----------
__global__ void zero_counter_kernel(int* __restrict__ c) {
    if (blockIdx.x == 0 && threadIdx.x == 0) c[0] = 0;
}

__global__ __launch_bounds__(256, 4) void edge_mlp_f32_kernel(
    const float* __restrict__ nf, const int* __restrict__ ei,
    const float* __restrict__ ef,
    const float* __restrict__ W1, const float* __restrict__ b1,
    const float* __restrict__ W2, const float* __restrict__ b2,
    const float* __restrict__ W3, const float* __restrict__ b3,
    int* __restrict__ counter, int* __restrict__ list, int cap,
    float* __restrict__ out)
{
    const int e = blockIdx.x * blockDim.x + threadIdx.x;
    if (e >= NE) return;
    const int is64 = (ei[1]==0)&(ei[3]==0)&(ei[5]==0)&(ei[7]==0);
    int si, ti;
    if (is64) { si = ei[2*(size_t)e]; ti = ei[2*((size_t)NE + e)]; }
    else      { si = ei[e];           ti = ei[NE + e]; }
    const float* srcp = nf + (size_t)si * D_NODE;
    const float* tgtp = nf + (size_t)ti * D_NODE;
    const float* efp  = ef + (size_t)e  * D_EDGE;

    float acc[HID];
    #pragma unroll
    for (int j = 0; j < HID; ++j) acc[j] = b1[j];
    #pragma unroll 1
    for (int kc = 0; kc < D_IN / 16; ++kc) {
        const float* base = (kc < 4) ? (srcp + kc * 16)
                          : (kc < 8) ? (tgtp + (kc - 4) * 16)
                                     : (efp  + (kc - 8) * 16);
        float c[16];
        #pragma unroll
        for (int q = 0; q < 4; ++q) {
            const float4 v = *reinterpret_cast<const float4*>(base + q * 4);
            c[q*4+0]=v.x; c[q*4+1]=v.y; c[q*4+2]=v.z; c[q*4+3]=v.w;
        }
        #pragma unroll
        for (int j = 0; j < HID; ++j)
            #pragma unroll
            for (int q = 0; q < 16; ++q)
                acc[j] = fmaf(c[q], W1[j*D_IN + kc*16 + q], acc[j]);
    }
    #pragma unroll
    for (int j = 0; j < HID; ++j) acc[j] = fmaxf(acc[j], 0.0f);

    float logit = b3[0];
    #pragma unroll 1
    for (int jj = 0; jj < H2C; ++jj) {
        float h = b2[jj];
        #pragma unroll
        for (int j = 0; j < HID; ++j) h = fmaf(acc[j], W2[jj*HID + j], h);
        logit = fmaf(fmaxf(h, 0.0f), W3[jj], logit);
    }
    const float score = 1.0f / (1.0f + expf(-logit));
    out[e] = score;
    out[(size_t)NE + e] = (score >= 0.5f) ? 1.0f : 0.0f;
    if (fabsf(logit) < EPS2) {
        const int idx = atomicAdd(counter, 1);
        if (idx < cap) list[idx] = e;
    }
}

__global__ __launch_bounds__(256) void fixup_list_f64_kernel(
    const float* __restrict__ nf, const int* __restrict__ ei,
    const float* __restrict__ ef,
    const float* __restrict__ W1, const float* __restrict__ b1,
    const float* __restrict__ W2, const float* __restrict__ b2,
    const float* __restrict__ W3, const float* __restrict__ b3,
    const int* __restrict__ counter, const int* __restrict__ list, int cap,
    float* __restrict__ out)
{
    __shared__ double fh[4][HID];
    __shared__ __attribute__((aligned(16))) float rows[4][160];
    const int wave = threadIdx.x >> 6, lane = threadIdx.x & 63;
    const int nwaves = (gridDim.x * blockDim.x) >> 6;
    const int wid = (blockIdx.x * blockDim.x + threadIdx.x) >> 6;
    int n = counter[0]; if (n > cap) n = cap;
    const int is64 = (ei[1]==0)&(ei[3]==0)&(ei[5]==0)&(ei[7]==0);

    for (int i = wid; i < n; i += nwaves) {
        const int e = list[i];
        int si, ti;
        if (is64) { si = ei[(size_t)2*e]; ti = ei[(size_t)2*(NE + (long long)e)]; }
        else      { si = ei[e];           ti = ei[NE + (size_t)e]; }
        const float* sp = nf + (size_t)si * D_NODE;
        const float* tp = nf + (size_t)ti * D_NODE;
        const float* ep = ef + (size_t)e * D_EDGE;

        if (lane < 16)      ((float4*)&rows[wave][0])[lane]        = ((const float4*)sp)[lane];
        else if (lane < 32) ((float4*)&rows[wave][64])[lane - 16]  = ((const float4*)tp)[lane - 16];
        else if (lane < 40) ((float4*)&rows[wave][128])[lane - 32] = ((const float4*)ep)[lane - 32];
        asm volatile("s_waitcnt lgkmcnt(0)" ::: "memory");

        const float* rw = rows[wave];
        double a0 = (double)b1[lane], a1 = 0.0, a2 = 0.0, a3 = 0.0;
        const float* w1r = W1 + (size_t)lane * D_IN;
        #pragma unroll 4
        for (int k = 0; k < 160; k += 4) {
            a0 = fma((double)rw[k+0], (double)w1r[k+0], a0);
            a1 = fma((double)rw[k+1], (double)w1r[k+1], a1);
            a2 = fma((double)rw[k+2], (double)w1r[k+2], a2);
            a3 = fma((double)rw[k+3], (double)w1r[k+3], a3);
        }
        fh[wave][lane] = fmax((a0 + a1) + (a2 + a3), 0.0);
        asm volatile("s_waitcnt lgkmcnt(0)" ::: "memory");

        double tsum = 0.0;
        if (lane < H2C) {
            double h0 = (double)b2[lane], h1 = 0.0, h2 = 0.0, h3 = 0.0;
            const float* w2r = W2 + (size_t)lane * HID;
            #pragma unroll 4
            for (int jj = 0; jj < 64; jj += 4) {
                h0 = fma(fh[wave][jj+0], (double)w2r[jj+0], h0);
                h1 = fma(fh[wave][jj+1], (double)w2r[jj+1], h1);
                h2 = fma(fh[wave][jj+2], (double)w2r[jj+2], h2);
                h3 = fma(fh[wave][jj+3], (double)w2r[jj+3], h3);
            }
            tsum = fmax((h0 + h1) + (h2 + h3), 0.0) * (double)W3[lane];
        }
        #pragma unroll
        for (int off = 1; off < 32; off <<= 1) tsum += __shfl_xor(tsum, off, 32);
        if (lane == 0) {
            const double logit = tsum + (double)b3[0];
            const float sc = (float)(1.0 / (1.0 + exp(-logit)));
            out[e] = sc;
            out[NE + (size_t)e] = (sc >= 0.5f) ? 1.0f : 0.0f;
        }
        asm volatile("s_waitcnt lgkmcnt(0)" ::: "memory");
    }
}

extern "C" void kernel_launch(void* const* d_in, const int* in_sizes, int n_in,
                              void* d_out, int out_size, void* d_ws, size_t ws_size,
                              hipStream_t stream) {
    const float* nf = (const float*)d_in[0];
    const int*   ei = (const int*)  d_in[1];
    const float* ef = (const float*)d_in[2];
    const float* W1 = (const float*)d_in[3];
    const float* b1 = (const float*)d_in[4];
    const float* W2 = (const float*)d_in[5];
    const float* b2 = (const float*)d_in[6];
    const float* W3 = (const float*)d_in[7];
    const float* b3 = (const float*)d_in[8];
    float* out = (float*)d_out;
    unsigned char* ws = (unsigned char*)d_ws;

    if (ws_size >= (size_t)WS_V11_MIN) {
        unsigned short* Uhi = (unsigned short*)(ws + WS_UHI);
        unsigned short* Ulo = (unsigned short*)(ws + WS_ULO);
        unsigned short* Vhi = (unsigned short*)(ws + WS_VHI);
        unsigned short* Vlo = (unsigned short*)(ws + WS_VLO);
        unsigned short* mask1 = (unsigned short*)(ws + WS_MASK);
        unsigned short* mask2 = (unsigned short*)(ws + WS_MASK2);
        hipLaunchKernelGGL(prep_uv_v9, dim3(N_NODES / 32), dim3(256), 0, stream,
                           nf, W1, b1, Uhi, Ulo, Vhi, Vlo);
        hipLaunchKernelGGL(prep_pack_v8, dim3(2), dim3(256), 0, stream, W1, W2, ws);
        hipLaunchKernelGGL(edge_mlp_v8_kernel, dim3((NE + 127) / 128), dim3(256), 0, stream,
                           ei, ef, b2, W3, b3,
                           (const unsigned short*)(ws + WS_A1_OFF),
                           (const unsigned short*)(ws + WS_A2_OFF),
                           Uhi, Vhi, mask1, out);
        // 2048 blocks x 4 waves = 8192 waves x CHUNK 8 = 65536 >= 62500 tiles
        hipLaunchKernelGGL(fixup1_v11, dim3(2048), dim3(256), 0, stream,
                           ei, ef, W1, W2, b2, W3, b3,
                           Uhi, Ulo, Vhi, Vlo, mask1, mask2, out);
        hipLaunchKernelGGL(fixup2_v11, dim3(2048), dim3(256), 0, stream,
                           nf, ei, ef, W1, b1, W2, b2, W3, b3, mask2, out);
    } else {
        int* counter = (int*)ws;
        long long cap_ll = ((long long)ws_size - 16) / 4;
        const int cap = (int)(cap_ll < 0 ? 0 : (cap_ll > NE ? NE : cap_ll));
        int* slist = (int*)(ws + 16);
        hipLaunchKernelGGL(zero_counter_kernel, dim3(1), dim3(64), 0, stream, counter);
        hipLaunchKernelGGL(edge_mlp_f32_kernel, dim3((NE + 255)/256), dim3(256), 0, stream,
                           nf, ei, ef, W1, b1, W2, b2, W3, b3, counter, slist, cap, out);
        hipLaunchKernelGGL(fixup_list_f64_kernel, dim3(512), dim3(256), 0, stream,
                           nf, ei, ef, W1, b1, W2, b2, W3, b3, counter, slist, cap, out);
    }
}